// Round 1
// baseline (823.998 us; speedup 1.0000x reference)
//
#include <hip/hip_runtime.h>

typedef unsigned short u16;
typedef __attribute__((ext_vector_type(8))) short short8;
typedef __attribute__((ext_vector_type(4))) float f32x4;

#define GLD16(g, l) __builtin_amdgcn_global_load_lds((const __attribute__((address_space(1))) void*)(g), (__attribute__((address_space(3))) void*)(l), 16, 0, 0)

__device__ __forceinline__ u16 f2bf(float f){
  unsigned x = __float_as_uint(f);
  return (u16)((x + 0x7FFFu + ((x >> 16) & 1u)) >> 16);
}
__device__ __forceinline__ float bf2f(u16 u){
  return __uint_as_float(((unsigned)u) << 16);
}

// ---------------- softmax over graph_bias rows -> bf16 attn ----------------
__global__ __launch_bounds__(256) void softmax_rows(const float* __restrict__ gb,
                                                    u16* __restrict__ attn){
  const int row = blockIdx.x;
  const float* rp = gb + (size_t)row * 4096;
  u16* op = attn + (size_t)row * 4096;
  const int t = threadIdx.x;
  float4 v[4];
  float mx = -3.4e38f;
#pragma unroll
  for(int k = 0; k < 4; k++){
    v[k] = *reinterpret_cast<const float4*>(rp + k*1024 + t*4);
    mx = fmaxf(mx, fmaxf(fmaxf(v[k].x, v[k].y), fmaxf(v[k].z, v[k].w)));
  }
#pragma unroll
  for(int off = 32; off > 0; off >>= 1) mx = fmaxf(mx, __shfl_xor(mx, off, 64));
  __shared__ float sred[4];
  __shared__ float sred2[4];
  const int wid = t >> 6, lane = t & 63;
  if(lane == 0) sred[wid] = mx;
  __syncthreads();
  mx = fmaxf(fmaxf(sred[0], sred[1]), fmaxf(sred[2], sred[3]));
  float s = 0.f;
#pragma unroll
  for(int k = 0; k < 4; k++){
    v[k].x = __expf(v[k].x - mx); v[k].y = __expf(v[k].y - mx);
    v[k].z = __expf(v[k].z - mx); v[k].w = __expf(v[k].w - mx);
    s += v[k].x + v[k].y + v[k].z + v[k].w;
  }
#pragma unroll
  for(int off = 32; off > 0; off >>= 1) s += __shfl_xor(s, off, 64);
  if(lane == 0) sred2[wid] = s;
  __syncthreads();
  s = sred2[0] + sred2[1] + sred2[2] + sred2[3];
  const float inv = 1.f / s;
#pragma unroll
  for(int k = 0; k < 4; k++){
    ushort4 o;
    o.x = f2bf(v[k].x * inv); o.y = f2bf(v[k].y * inv);
    o.z = f2bf(v[k].z * inv); o.w = f2bf(v[k].w * inv);
    *reinterpret_cast<ushort4*>(op + k*1024 + t*4) = o;
  }
}

// ---------------- fp32 vector GEMM: C = A @ B^T (both row-major, K-contig) ----------------
// BM=BN=64, BK=16, 256 threads, 4x4 acc/thread. LDS staged transposed for b128 reads.
__global__ __launch_bounds__(256) void sgemm_bt(const float* __restrict__ A, int lda,
                                                const float* __restrict__ Bw, int ldb,
                                                float* __restrict__ C, int ldc, int K){
  __shared__ float As[16][64];
  __shared__ float Bs[16][64];
  const int t = threadIdx.x;
  const int bm = blockIdx.x << 6, bn = blockIdx.y << 6;
  const int lr = t >> 2, lc = (t & 3) << 2;
  const int tr = t >> 4, tc = t & 15;
  float acc[4][4] = {};
  for(int k0 = 0; k0 < K; k0 += 16){
    float4 av = *reinterpret_cast<const float4*>(A  + (size_t)(bm + lr) * lda + k0 + lc);
    float4 bv = *reinterpret_cast<const float4*>(Bw + (size_t)(bn + lr) * ldb + k0 + lc);
    __syncthreads();
    As[lc+0][lr] = av.x; As[lc+1][lr] = av.y; As[lc+2][lr] = av.z; As[lc+3][lr] = av.w;
    Bs[lc+0][lr] = bv.x; Bs[lc+1][lr] = bv.y; Bs[lc+2][lr] = bv.z; Bs[lc+3][lr] = bv.w;
    __syncthreads();
#pragma unroll
    for(int kk = 0; kk < 16; kk++){
      const float4 a4 = *reinterpret_cast<const float4*>(&As[kk][tr << 2]);
      const float4 b4 = *reinterpret_cast<const float4*>(&Bs[kk][tc << 2]);
      const float av_[4] = {a4.x, a4.y, a4.z, a4.w};
      const float bv_[4] = {b4.x, b4.y, b4.z, b4.w};
#pragma unroll
      for(int i = 0; i < 4; i++)
#pragma unroll
        for(int j = 0; j < 4; j++) acc[i][j] = fmaf(av_[i], bv_[j], acc[i][j]);
    }
  }
#pragma unroll
  for(int i = 0; i < 4; i++){
    float4 o = {acc[i][0], acc[i][1], acc[i][2], acc[i][3]};
    *reinterpret_cast<float4*>(C + (size_t)(bm + (tr << 2) + i) * ldc + bn + (tc << 2)) = o;
  }
}

// ---------------- up-projection (K=64) + feature map; MODE 0=Q,1=K(+ksum),2=V ----------------
// Q stored (B,H,N,64) bf16; K,V stored transposed (B,H,64,N) bf16.
template<int MODE>
__global__ __launch_bounds__(256) void up_feature(const float* __restrict__ low,
                                                  const float* __restrict__ Wup,
                                                  u16* __restrict__ outp,
                                                  float* __restrict__ ksum){
  __shared__ float in_t[64][64];   // [k][row]
  __shared__ float wt_t[64][64];   // [k][col]
  __shared__ u16 res[64][68];      // [col][row] for transposed store
  const int rb = blockIdx.x;       // global row tile (b*64 tiles)
  const int h  = blockIdx.y;
  const int t  = threadIdx.x;
  const int r0 = rb << 6;
  const int b  = r0 >> 12;
  const int n0 = r0 & 4095;
  const size_t bh = (size_t)(b * 8 + h);
#pragma unroll
  for(int q = 0; q < 4; q++){
    const int row = (q << 4) + (t >> 4);
    const int c4  = (t & 15) << 2;
    float4 v = *reinterpret_cast<const float4*>(low + (size_t)(r0 + row) * 192 + MODE * 64 + c4);
    in_t[c4+0][row] = v.x; in_t[c4+1][row] = v.y; in_t[c4+2][row] = v.z; in_t[c4+3][row] = v.w;
    float4 w = *reinterpret_cast<const float4*>(Wup + (size_t)(h * 64 + row) * 64 + c4);
    wt_t[c4+0][row] = w.x; wt_t[c4+1][row] = w.y; wt_t[c4+2][row] = w.z; wt_t[c4+3][row] = w.w;
  }
  __syncthreads();
  const int tr = t >> 4, tc = t & 15;
  float acc[4][4] = {};
#pragma unroll
  for(int kk = 0; kk < 64; kk++){
    const float4 a4 = *reinterpret_cast<const float4*>(&in_t[kk][tr << 2]);
    const float4 b4 = *reinterpret_cast<const float4*>(&wt_t[kk][tc << 2]);
    const float av_[4] = {a4.x, a4.y, a4.z, a4.w};
    const float bv_[4] = {b4.x, b4.y, b4.z, b4.w};
#pragma unroll
    for(int i = 0; i < 4; i++)
#pragma unroll
      for(int j = 0; j < 4; j++) acc[i][j] = fmaf(av_[i], bv_[j], acc[i][j]);
  }
  if(MODE < 2){
#pragma unroll
    for(int i = 0; i < 4; i++)
#pragma unroll
      for(int j = 0; j < 4; j++) acc[i][j] = acc[i][j] > 0.f ? acc[i][j] + 1.f : __expf(acc[i][j]);
  }
  if(MODE == 0){
    const size_t qbase = (bh << 12) + n0;
#pragma unroll
    for(int i = 0; i < 4; i++){
      ushort4 o;
      o.x = f2bf(acc[i][0]); o.y = f2bf(acc[i][1]); o.z = f2bf(acc[i][2]); o.w = f2bf(acc[i][3]);
      *reinterpret_cast<ushort4*>(outp + ((qbase + (tr << 2) + i) << 6) + (tc << 2)) = o;
    }
  } else {
#pragma unroll
    for(int i = 0; i < 4; i++)
#pragma unroll
      for(int j = 0; j < 4; j++) res[(tc << 2) + j][(tr << 2) + i] = f2bf(acc[i][j]);
    __syncthreads();
    if(MODE == 1 && t < 64){
      float s = 0.f;
      for(int r = 0; r < 64; r++) s += bf2f(res[t][r]);
      atomicAdd(ksum + (bh << 6) + t, s);
    }
    const int c = t >> 2, seg = t & 3;
    const size_t gbase = ((bh << 6) + c) << 12;
#pragma unroll
    for(int q = 0; q < 4; q++){
      ushort4 o = *reinterpret_cast<const ushort4*>(&res[c][seg * 16 + q * 4]);
      *reinterpret_cast<ushort4*>(outp + gbase + n0 + seg * 16 + q * 4) = o;
    }
  }
}

// ---------------- KVt[bh][D'][d] = sum_n Vt[D'][n]*Kt[d][n], split-K atomics ----------------
__global__ __launch_bounds__(256) void kvt_kernel(const u16* __restrict__ Kt,
                                                  const u16* __restrict__ Vt,
                                                  float* __restrict__ KVt){
  __shared__ float ks[64][64];  // [n_local][d]
  __shared__ float vs[64][64];  // [n_local][D']
  const int bhi = blockIdx.x, sp = blockIdx.y;
  const size_t baseK = (size_t)bhi << 18;   // bh*64*4096
  const int t = threadIdx.x;
  const int tr = t >> 4, tc = t & 15;
  float acc[4][4] = {};
  for(int ch = 0; ch < 8; ch++){
    const int n0 = (sp << 9) + (ch << 6);
    ushort4 ku[4], vu[4];
#pragma unroll
    for(int q = 0; q < 4; q++){
      const int d  = (q << 4) + (t >> 4);
      const int c4 = (t & 15) << 2;
      ku[q] = *reinterpret_cast<const ushort4*>(Kt + baseK + ((size_t)d << 12) + n0 + c4);
      vu[q] = *reinterpret_cast<const ushort4*>(Vt + baseK + ((size_t)d << 12) + n0 + c4);
    }
    __syncthreads();
#pragma unroll
    for(int q = 0; q < 4; q++){
      const int d  = (q << 4) + (t >> 4);
      const int c4 = (t & 15) << 2;
      ks[c4+0][d] = bf2f(ku[q].x); ks[c4+1][d] = bf2f(ku[q].y); ks[c4+2][d] = bf2f(ku[q].z); ks[c4+3][d] = bf2f(ku[q].w);
      vs[c4+0][d] = bf2f(vu[q].x); vs[c4+1][d] = bf2f(vu[q].y); vs[c4+2][d] = bf2f(vu[q].z); vs[c4+3][d] = bf2f(vu[q].w);
    }
    __syncthreads();
#pragma unroll
    for(int kk = 0; kk < 64; kk++){
      const float4 a4 = *reinterpret_cast<const float4*>(&vs[kk][tr << 2]);
      const float4 b4 = *reinterpret_cast<const float4*>(&ks[kk][tc << 2]);
      const float av_[4] = {a4.x, a4.y, a4.z, a4.w};
      const float bv_[4] = {b4.x, b4.y, b4.z, b4.w};
#pragma unroll
      for(int i = 0; i < 4; i++)
#pragma unroll
        for(int j = 0; j < 4; j++) acc[i][j] = fmaf(av_[i], bv_[j], acc[i][j]);
    }
  }
#pragma unroll
  for(int i = 0; i < 4; i++)
#pragma unroll
    for(int j = 0; j < 4; j++)
      atomicAdd(KVt + ((size_t)bhi << 12) + (size_t)((tr << 2) + i) * 64 + (tc << 2) + j, acc[i][j]);
}

// ---------------- bias branch GEMM: C[i,col] = 0.1 * sum_k attn[i,k] * Vt_all[col,k] ----------------
// m97-style: 128x128 tile, BK=32, 4 waves (2x2), 16x16x32 bf16 MFMA, global_load_lds w=16.
__global__ __launch_bounds__(256) void bias_gemm(const u16* __restrict__ Am,
                                                 const u16* __restrict__ Bm,
                                                 float* __restrict__ Co){
  __shared__ u16 As[128 * 32];
  __shared__ u16 Bs[128 * 32];
  const int t = threadIdx.x;
  const int wid = t >> 6, lane = t & 63;
  const int wr = wid >> 1, wc = wid & 1;
  const int bm = blockIdx.x << 7, bn = blockIdx.y << 7;
  f32x4 acc[4][4];
#pragma unroll
  for(int m = 0; m < 4; m++)
#pragma unroll
    for(int n = 0; n < 4; n++) acc[m][n] = f32x4{0.f, 0.f, 0.f, 0.f};
  const int frow = lane & 15;
  const int kg8  = (lane >> 4) << 3;
  const int c0 = t, c1 = t + 256;
  for(int k0 = 0; k0 < 4096; k0 += 32){
    GLD16(Am + ((size_t)(bm + (c0 >> 2)) << 12) + k0 + ((c0 & 3) << 3), ((char*)As) + (wid << 10));
    GLD16(Am + ((size_t)(bm + (c1 >> 2)) << 12) + k0 + ((c1 & 3) << 3), ((char*)As) + 4096 + (wid << 10));
    GLD16(Bm + ((size_t)(bn + (c0 >> 2)) << 12) + k0 + ((c0 & 3) << 3), ((char*)Bs) + (wid << 10));
    GLD16(Bm + ((size_t)(bn + (c1 >> 2)) << 12) + k0 + ((c1 & 3) << 3), ((char*)Bs) + 4096 + (wid << 10));
    __syncthreads();
    short8 af[4], bfr[4];
#pragma unroll
    for(int m = 0; m < 4; m++){
      af[m]  = *reinterpret_cast<const short8*>(As + (((wr << 6) + (m << 4) + frow) << 5) + kg8);
      bfr[m] = *reinterpret_cast<const short8*>(Bs + (((wc << 6) + (m << 4) + frow) << 5) + kg8);
    }
#pragma unroll
    for(int m = 0; m < 4; m++)
#pragma unroll
      for(int n = 0; n < 4; n++)
        acc[m][n] = __builtin_amdgcn_mfma_f32_16x16x32_bf16(af[m], bfr[n], acc[m][n], 0, 0, 0);
    __syncthreads();
  }
  const int cn = lane & 15, rb4 = (lane >> 4) << 2;
#pragma unroll
  for(int m = 0; m < 4; m++){
    const int row0 = bm + (wr << 6) + (m << 4) + rb4;
#pragma unroll
    for(int n = 0; n < 4; n++){
      const int col = bn + (wc << 6) + (n << 4) + cn;
      float* ob = Co + ((size_t)(col >> 9) << 21) + (size_t)(col & 511);
#pragma unroll
      for(int j = 0; j < 4; j++)
        ob[(size_t)(row0 + j) << 9] = 0.1f * acc[m][n][j];
    }
  }
}

// ---------------- linear attention: out += (Q @ KVt^T) / clip(Q . Ksum) ----------------
__global__ __launch_bounds__(256) void linattn(const u16* __restrict__ Qb,
                                               const float* __restrict__ KVt,
                                               const float* __restrict__ Ksum,
                                               float* __restrict__ outc){
  __shared__ float qs[64][64];   // [d][n_local]
  __shared__ float kvs[64][64];  // [d][D']
  __shared__ float nrm[64];
  __shared__ float ksl[64];
  const int nblk = blockIdx.x, bhi = blockIdx.y;
  const int b = bhi >> 3, h = bhi & 7;
  const int n0 = nblk << 6;
  const int t = threadIdx.x;
#pragma unroll
  for(int q = 0; q < 4; q++){
    const int row = (q << 4) + (t >> 4);
    const int c4  = (t & 15) << 2;
    ushort4 u = *reinterpret_cast<const ushort4*>(Qb + ((((size_t)bhi << 12) + n0 + row) << 6) + c4);
    qs[c4+0][row] = bf2f(u.x); qs[c4+1][row] = bf2f(u.y); qs[c4+2][row] = bf2f(u.z); qs[c4+3][row] = bf2f(u.w);
    const int Dp = row;
    float4 v = *reinterpret_cast<const float4*>(KVt + ((size_t)bhi << 12) + (Dp << 6) + c4);
    kvs[c4+0][Dp] = v.x; kvs[c4+1][Dp] = v.y; kvs[c4+2][Dp] = v.z; kvs[c4+3][Dp] = v.w;
  }
  if(t < 64) ksl[t] = Ksum[((size_t)bhi << 6) + t];
  __syncthreads();
  if(t < 64){
    float s = 0.f;
    for(int d = 0; d < 64; d++) s = fmaf(qs[d][t], ksl[d], s);
    nrm[t] = fmaxf(s, 1e-6f);
  }
  __syncthreads();
  const int tr = t >> 4, tc = t & 15;
  float acc[4][4] = {};
#pragma unroll
  for(int kk = 0; kk < 64; kk++){
    const float4 a4 = *reinterpret_cast<const float4*>(&qs[kk][tr << 2]);
    const float4 b4 = *reinterpret_cast<const float4*>(&kvs[kk][tc << 2]);
    const float av_[4] = {a4.x, a4.y, a4.z, a4.w};
    const float bv_[4] = {b4.x, b4.y, b4.z, b4.w};
#pragma unroll
    for(int i = 0; i < 4; i++)
#pragma unroll
      for(int j = 0; j < 4; j++) acc[i][j] = fmaf(av_[i], bv_[j], acc[i][j]);
  }
#pragma unroll
  for(int i = 0; i < 4; i++){
    const int gn = n0 + (tr << 2) + i;
    const float inv = 1.f / nrm[(tr << 2) + i];
    const size_t oi = (((size_t)b << 12) + gn) * 512 + h * 64 + (tc << 2);
    float4 p = *reinterpret_cast<const float4*>(outc + oi);
    p.x = fmaf(acc[i][0], inv, p.x);
    p.y = fmaf(acc[i][1], inv, p.y);
    p.z = fmaf(acc[i][2], inv, p.z);
    p.w = fmaf(acc[i][3], inv, p.w);
    *reinterpret_cast<float4*>(outc + oi) = p;
  }
}

extern "C" void kernel_launch(void* const* d_in, const int* in_sizes, int n_in,
                              void* d_out, int out_size, void* d_ws, size_t ws_size,
                              hipStream_t stream){
  const float* x    = (const float*)d_in[0];
  const float* gb   = (const float*)d_in[1];
  const float* w_qd = (const float*)d_in[2];
  const float* w_qu = (const float*)d_in[3];
  const float* w_kd = (const float*)d_in[4];
  const float* w_ku = (const float*)d_in[5];
  const float* w_vd = (const float*)d_in[6];
  const float* w_vu = (const float*)d_in[7];
  const float* w_od = (const float*)d_in[8];
  const float* w_ou = (const float*)d_in[9];
  float* out = (float*)d_out;
  char* ws = (char*)d_ws;

  float* qkv_low = (float*)(ws);                    // 32768*192*4  = 25165824
  u16*   Qb      = (u16*)  (ws + 25165824);         // 33554432
  u16*   Kt      = (u16*)  (ws + 58720256);         // 33554432
  u16*   Vt      = (u16*)  (ws + 92274688);         // 33554432
  u16*   attn    = (u16*)  (ws + 125829120);        // 33554432
  float* KVt     = (float*)(ws + 159383552);        // 1048576
  float* Ksum    = (float*)(ws + 160432128);        // 16384
  float* outlow  = (float*)(ws + 160448512);        // 8388608

  hipMemsetAsync(KVt, 0, 1048576 + 16384, stream);

  softmax_rows<<<4096, 256, 0, stream>>>(gb, attn);

  // down projections (C = x @ Wd^T), stripes of qkv_low (ldc=192)
  sgemm_bt<<<dim3(512, 1), 256, 0, stream>>>(x, 512, w_qd, 512, qkv_low + 0,   192, 512);
  sgemm_bt<<<dim3(512, 1), 256, 0, stream>>>(x, 512, w_kd, 512, qkv_low + 64,  192, 512);
  sgemm_bt<<<dim3(512, 1), 256, 0, stream>>>(x, 512, w_vd, 512, qkv_low + 128, 192, 512);

  // up projections + feature map; K/V transposed (B,H,64,N); K_sum fused
  up_feature<0><<<dim3(512, 8), 256, 0, stream>>>(qkv_low, w_qu, Qb, nullptr);
  up_feature<1><<<dim3(512, 8), 256, 0, stream>>>(qkv_low, w_ku, Kt, Ksum);
  up_feature<2><<<dim3(512, 8), 256, 0, stream>>>(qkv_low, w_vu, Vt, nullptr);

  kvt_kernel<<<dim3(64, 8), 256, 0, stream>>>(Kt, Vt, KVt);

  // bias branch: writes 0.1*bias_out into d_out (full coverage)
  bias_gemm<<<dim3(32, 32), 256, 0, stream>>>(attn, Vt, out);

  // linear attention adds into d_out
  linattn<<<dim3(64, 64), 256, 0, stream>>>(Qb, KVt, Ksum, out);

  // final low-rank projection (fp32)
  sgemm_bt<<<dim3(512, 1), 256, 0, stream>>>(out,    512, w_od, 512, outlow, 64,  512);
  sgemm_bt<<<dim3(512, 8), 256, 0, stream>>>(outlow, 64,  w_ou, 64,  out,    512, 64);
}

// Round 2
// 621.463 us; speedup vs baseline: 1.3259x; 1.3259x over previous
//
#include <hip/hip_runtime.h>

typedef unsigned short u16;
typedef __attribute__((ext_vector_type(8))) short short8;
typedef __attribute__((ext_vector_type(4))) float f32x4;

#define GLD16(g, l) __builtin_amdgcn_global_load_lds((const __attribute__((address_space(1))) void*)(g), (__attribute__((address_space(3))) void*)(l), 16, 0, 0)

__device__ __forceinline__ u16 f2bf(float f){
  unsigned x = __float_as_uint(f);
  return (u16)((x + 0x7FFFu + ((x >> 16) & 1u)) >> 16);
}
__device__ __forceinline__ float bf2f(u16 u){
  return __uint_as_float(((unsigned)u) << 16);
}

// ---------------- softmax over graph_bias rows -> bf16 attn ----------------
__global__ __launch_bounds__(256) void softmax_rows(const float* __restrict__ gb,
                                                    u16* __restrict__ attn){
  const int row = blockIdx.x;
  const float* rp = gb + (size_t)row * 4096;
  u16* op = attn + (size_t)row * 4096;
  const int t = threadIdx.x;
  float4 v[4];
  float mx = -3.4e38f;
#pragma unroll
  for(int k = 0; k < 4; k++){
    v[k] = *reinterpret_cast<const float4*>(rp + k*1024 + t*4);
    mx = fmaxf(mx, fmaxf(fmaxf(v[k].x, v[k].y), fmaxf(v[k].z, v[k].w)));
  }
#pragma unroll
  for(int off = 32; off > 0; off >>= 1) mx = fmaxf(mx, __shfl_xor(mx, off, 64));
  __shared__ float sred[4];
  __shared__ float sred2[4];
  const int wid = t >> 6, lane = t & 63;
  if(lane == 0) sred[wid] = mx;
  __syncthreads();
  mx = fmaxf(fmaxf(sred[0], sred[1]), fmaxf(sred[2], sred[3]));
  float s = 0.f;
#pragma unroll
  for(int k = 0; k < 4; k++){
    v[k].x = __expf(v[k].x - mx); v[k].y = __expf(v[k].y - mx);
    v[k].z = __expf(v[k].z - mx); v[k].w = __expf(v[k].w - mx);
    s += v[k].x + v[k].y + v[k].z + v[k].w;
  }
#pragma unroll
  for(int off = 32; off > 0; off >>= 1) s += __shfl_xor(s, off, 64);
  if(lane == 0) sred2[wid] = s;
  __syncthreads();
  s = sred2[0] + sred2[1] + sred2[2] + sred2[3];
  const float inv = 1.f / s;
#pragma unroll
  for(int k = 0; k < 4; k++){
    ushort4 o;
    o.x = f2bf(v[k].x * inv); o.y = f2bf(v[k].y * inv);
    o.z = f2bf(v[k].z * inv); o.w = f2bf(v[k].w * inv);
    *reinterpret_cast<ushort4*>(op + k*1024 + t*4) = o;
  }
}

// ---------------- combine low-rank pair: W = wu(512x64) @ wd(64x512), bf16 out ----------------
__global__ __launch_bounds__(256) void combine_w(const float* __restrict__ wu,
                                                 const float* __restrict__ wd,
                                                 u16* __restrict__ dst){
  __shared__ float au[64][68];  // [r][o]
  __shared__ float bd[64][68];  // [r][i]
  const int t = threadIdx.x;
  const int o0 = blockIdx.x << 6, i0 = blockIdx.y << 6;
#pragma unroll
  for(int q = 0; q < 4; q++){
    const int row = (q << 4) + (t >> 4);
    const int c4  = (t & 15) << 2;
    float4 u = *reinterpret_cast<const float4*>(wu + (size_t)(o0 + row) * 64 + c4);
    au[c4+0][row] = u.x; au[c4+1][row] = u.y; au[c4+2][row] = u.z; au[c4+3][row] = u.w;
    float4 v = *reinterpret_cast<const float4*>(wd + (size_t)row * 512 + i0 + c4);
    bd[row][c4+0] = v.x; bd[row][c4+1] = v.y; bd[row][c4+2] = v.z; bd[row][c4+3] = v.w;
  }
  __syncthreads();
  const int tr = t >> 4, tc = t & 15;
  float acc[4][4] = {};
#pragma unroll
  for(int kk = 0; kk < 64; kk++){
    const float4 a4 = *reinterpret_cast<const float4*>(&au[kk][tr << 2]);
    const float4 b4 = *reinterpret_cast<const float4*>(&bd[kk][tc << 2]);
    const float av_[4] = {a4.x, a4.y, a4.z, a4.w};
    const float bv_[4] = {b4.x, b4.y, b4.z, b4.w};
#pragma unroll
    for(int i = 0; i < 4; i++)
#pragma unroll
      for(int j = 0; j < 4; j++) acc[i][j] = fmaf(av_[i], bv_[j], acc[i][j]);
  }
#pragma unroll
  for(int i = 0; i < 4; i++){
    ushort4 o;
    o.x = f2bf(acc[i][0]); o.y = f2bf(acc[i][1]); o.z = f2bf(acc[i][2]); o.w = f2bf(acc[i][3]);
    *reinterpret_cast<ushort4*>(dst + (size_t)(o0 + (tr << 2) + i) * 512 + i0 + (tc << 2)) = o;
  }
}

// ---------------- x fp32 -> bf16 ----------------
__global__ __launch_bounds__(256) void cast_x(const float* __restrict__ x, u16* __restrict__ xb){
  const size_t i = ((size_t)blockIdx.x * 256 + threadIdx.x) * 8;
  float4 a = *reinterpret_cast<const float4*>(x + i);
  float4 b = *reinterpret_cast<const float4*>(x + i + 4);
  ushort4 o0 = {f2bf(a.x), f2bf(a.y), f2bf(a.z), f2bf(a.w)};
  ushort4 o1 = {f2bf(b.x), f2bf(b.y), f2bf(b.z), f2bf(b.w)};
  *reinterpret_cast<ushort4*>(xb + i) = o0;
  *reinterpret_cast<ushort4*>(xb + i + 4) = o1;
}

// ---------------- QKV GEMM: C = xb(32768x512) @ Wqkv^T(1536x512); epilogue: feature map,
// transposed store to Qt/Kt/Vt (BH,64,N), fused Ksum. m97 structure. ----------------
__global__ __launch_bounds__(256) void qkv_gemm(const u16* __restrict__ Am, const u16* __restrict__ Bm,
                                                u16* __restrict__ Qt, u16* __restrict__ Kt,
                                                u16* __restrict__ Vt, float* __restrict__ Ksum){
  __shared__ u16 As[128 * 32];
  __shared__ u16 Bs[128 * 32];
  const int t = threadIdx.x;
  const int wid = t >> 6, lane = t & 63;
  const int wr = wid >> 1, wc = wid & 1;
  const int bm = blockIdx.x << 7, bn = blockIdx.y << 7;
  f32x4 acc[4][4];
#pragma unroll
  for(int m = 0; m < 4; m++)
#pragma unroll
    for(int n = 0; n < 4; n++) acc[m][n] = f32x4{0.f, 0.f, 0.f, 0.f};
  const int frow = lane & 15;
  const int kg8  = (lane >> 4) << 3;
  const int c0 = t, c1 = t + 256;
  for(int k0 = 0; k0 < 512; k0 += 32){
    GLD16(Am + (size_t)(bm + (c0 >> 2)) * 512 + k0 + ((c0 & 3) << 3), ((char*)As) + (wid << 10));
    GLD16(Am + (size_t)(bm + (c1 >> 2)) * 512 + k0 + ((c1 & 3) << 3), ((char*)As) + 4096 + (wid << 10));
    GLD16(Bm + (size_t)(bn + (c0 >> 2)) * 512 + k0 + ((c0 & 3) << 3), ((char*)Bs) + (wid << 10));
    GLD16(Bm + (size_t)(bn + (c1 >> 2)) * 512 + k0 + ((c1 & 3) << 3), ((char*)Bs) + 4096 + (wid << 10));
    __syncthreads();
    short8 af[4], bfr[4];
#pragma unroll
    for(int m = 0; m < 4; m++){
      af[m]  = *reinterpret_cast<const short8*>(As + (((wr << 6) + (m << 4) + frow) << 5) + kg8);
      bfr[m] = *reinterpret_cast<const short8*>(Bs + (((wc << 6) + (m << 4) + frow) << 5) + kg8);
    }
#pragma unroll
    for(int m = 0; m < 4; m++)
#pragma unroll
      for(int n = 0; n < 4; n++)
        acc[m][n] = __builtin_amdgcn_mfma_f32_16x16x32_bf16(af[m], bfr[n], acc[m][n], 0, 0, 0);
    __syncthreads();
  }
  const int cn = lane & 15, rb4 = (lane >> 4) << 2;
  const int p = bn >> 9;                     // 0=Q, 1=K, 2=V (128-tile within 512)
  u16* base = (p == 0) ? Qt : ((p == 1) ? Kt : Vt);
  const int b = bm >> 12;
#pragma unroll
  for(int nf = 0; nf < 4; nf++){
    const int col = bn + (wc << 6) + (nf << 4) + cn;
    const int c = col & 511;
    const int bh = (b << 3) + (c >> 6);
    const int d = c & 63;
    u16* rowp = base + ((((size_t)bh << 6) + d) << 12);
    float ks = 0.f;
#pragma unroll
    for(int mf = 0; mf < 4; mf++){
      const int nn0 = (bm & 4095) + (wr << 6) + (mf << 4) + rb4;
      float v0 = acc[mf][nf][0], v1 = acc[mf][nf][1], v2 = acc[mf][nf][2], v3 = acc[mf][nf][3];
      if(p < 2){
        v0 = v0 > 0.f ? v0 + 1.f : __expf(v0);
        v1 = v1 > 0.f ? v1 + 1.f : __expf(v1);
        v2 = v2 > 0.f ? v2 + 1.f : __expf(v2);
        v3 = v3 > 0.f ? v3 + 1.f : __expf(v3);
      }
      if(p == 1) ks += v0 + v1 + v2 + v3;
      ushort4 o = {f2bf(v0), f2bf(v1), f2bf(v2), f2bf(v3)};
      *reinterpret_cast<ushort4*>(rowp + nn0) = o;
    }
    if(p == 1){
      ks += __shfl_xor(ks, 16);
      ks += __shfl_xor(ks, 32);
      if(lane < 16) atomicAdd(Ksum + ((size_t)bh << 6) + d, ks);
    }
  }
}

// ---------------- KVt[bh][D'][d] = sum_n Vt[D'][n]*Kt[d][n], split-K atomics (fp32) ----------------
__global__ __launch_bounds__(256) void kvt_kernel(const u16* __restrict__ Kt,
                                                  const u16* __restrict__ Vt,
                                                  float* __restrict__ KVt){
  __shared__ float ks[64][64];
  __shared__ float vs[64][64];
  const int bhi = blockIdx.x, sp = blockIdx.y;
  const size_t baseK = (size_t)bhi << 18;
  const int t = threadIdx.x;
  const int tr = t >> 4, tc = t & 15;
  float acc[4][4] = {};
  for(int ch = 0; ch < 8; ch++){
    const int n0 = (sp << 9) + (ch << 6);
    ushort4 ku[4], vu[4];
#pragma unroll
    for(int q = 0; q < 4; q++){
      const int d  = (q << 4) + (t >> 4);
      const int c4 = (t & 15) << 2;
      ku[q] = *reinterpret_cast<const ushort4*>(Kt + baseK + ((size_t)d << 12) + n0 + c4);
      vu[q] = *reinterpret_cast<const ushort4*>(Vt + baseK + ((size_t)d << 12) + n0 + c4);
    }
    __syncthreads();
#pragma unroll
    for(int q = 0; q < 4; q++){
      const int d  = (q << 4) + (t >> 4);
      const int c4 = (t & 15) << 2;
      ks[c4+0][d] = bf2f(ku[q].x); ks[c4+1][d] = bf2f(ku[q].y); ks[c4+2][d] = bf2f(ku[q].z); ks[c4+3][d] = bf2f(ku[q].w);
      vs[c4+0][d] = bf2f(vu[q].x); vs[c4+1][d] = bf2f(vu[q].y); vs[c4+2][d] = bf2f(vu[q].z); vs[c4+3][d] = bf2f(vu[q].w);
    }
    __syncthreads();
#pragma unroll
    for(int kk = 0; kk < 64; kk++){
      const float4 a4 = *reinterpret_cast<const float4*>(&vs[kk][tr << 2]);
      const float4 b4 = *reinterpret_cast<const float4*>(&ks[kk][tc << 2]);
      const float av_[4] = {a4.x, a4.y, a4.z, a4.w};
      const float bv_[4] = {b4.x, b4.y, b4.z, b4.w};
#pragma unroll
      for(int i = 0; i < 4; i++)
#pragma unroll
        for(int j = 0; j < 4; j++) acc[i][j] = fmaf(av_[i], bv_[j], acc[i][j]);
    }
  }
#pragma unroll
  for(int i = 0; i < 4; i++)
#pragma unroll
    for(int j = 0; j < 4; j++)
      atomicAdd(KVt + ((size_t)bhi << 12) + (size_t)((tr << 2) + i) * 64 + (tc << 2) + j, acc[i][j]);
}

// ---------------- bias branch GEMM: mid[i,col] = 0.1 * sum_k attn[i,k] * Vt_all[col,k] ----------------
__global__ __launch_bounds__(256) void bias_gemm(const u16* __restrict__ Am,
                                                 const u16* __restrict__ Bm,
                                                 float* __restrict__ Co){
  __shared__ u16 As[128 * 32];
  __shared__ u16 Bs[128 * 32];
  const int t = threadIdx.x;
  const int wid = t >> 6, lane = t & 63;
  const int wr = wid >> 1, wc = wid & 1;
  const int bm = blockIdx.x << 7, bn = blockIdx.y << 7;
  f32x4 acc[4][4];
#pragma unroll
  for(int m = 0; m < 4; m++)
#pragma unroll
    for(int n = 0; n < 4; n++) acc[m][n] = f32x4{0.f, 0.f, 0.f, 0.f};
  const int frow = lane & 15;
  const int kg8  = (lane >> 4) << 3;
  const int c0 = t, c1 = t + 256;
  for(int k0 = 0; k0 < 4096; k0 += 32){
    GLD16(Am + ((size_t)(bm + (c0 >> 2)) << 12) + k0 + ((c0 & 3) << 3), ((char*)As) + (wid << 10));
    GLD16(Am + ((size_t)(bm + (c1 >> 2)) << 12) + k0 + ((c1 & 3) << 3), ((char*)As) + 4096 + (wid << 10));
    GLD16(Bm + ((size_t)(bn + (c0 >> 2)) << 12) + k0 + ((c0 & 3) << 3), ((char*)Bs) + (wid << 10));
    GLD16(Bm + ((size_t)(bn + (c1 >> 2)) << 12) + k0 + ((c1 & 3) << 3), ((char*)Bs) + 4096 + (wid << 10));
    __syncthreads();
    short8 af[4], bfr[4];
#pragma unroll
    for(int m = 0; m < 4; m++){
      af[m]  = *reinterpret_cast<const short8*>(As + (((wr << 6) + (m << 4) + frow) << 5) + kg8);
      bfr[m] = *reinterpret_cast<const short8*>(Bs + (((wc << 6) + (m << 4) + frow) << 5) + kg8);
    }
#pragma unroll
    for(int m = 0; m < 4; m++)
#pragma unroll
      for(int n = 0; n < 4; n++)
        acc[m][n] = __builtin_amdgcn_mfma_f32_16x16x32_bf16(af[m], bfr[n], acc[m][n], 0, 0, 0);
    __syncthreads();
  }
  const int cn = lane & 15, rb4 = (lane >> 4) << 2;
#pragma unroll
  for(int m = 0; m < 4; m++){
    const int row0 = bm + (wr << 6) + (m << 4) + rb4;
#pragma unroll
    for(int n = 0; n < 4; n++){
      const int col = bn + (wc << 6) + (n << 4) + cn;
      float* ob = Co + ((size_t)(col >> 9) << 21) + (size_t)(col & 511);
#pragma unroll
      for(int j = 0; j < 4; j++)
        ob[(size_t)(row0 + j) << 9] = 0.1f * acc[m][n][j];
    }
  }
}

// ---------------- linear attention: midb = bf16( mid + (Q @ KVt^T)/clip(Q.Ksum) ) ----------------
__global__ __launch_bounds__(256) void linattn(const u16* __restrict__ Qt,
                                               const float* __restrict__ KVt,
                                               const float* __restrict__ Ksum,
                                               const float* __restrict__ mid,
                                               u16* __restrict__ midb){
  __shared__ float qs[64][64];   // [d][n_local]
  __shared__ float kvs[64][64];  // [d][D']
  __shared__ float nrm[64];
  __shared__ float ksl[64];
  const int nblk = blockIdx.x, bhi = blockIdx.y;
  const int b = bhi >> 3, h = bhi & 7;
  const int n0 = nblk << 6;
  const int t = threadIdx.x;
#pragma unroll
  for(int q = 0; q < 4; q++){
    const int row = (q << 4) + (t >> 4);
    const int c4  = (t & 15) << 2;
    ushort4 u = *reinterpret_cast<const ushort4*>(Qt + ((((size_t)bhi << 6) + row) << 12) + n0 + c4);
    qs[row][c4+0] = bf2f(u.x); qs[row][c4+1] = bf2f(u.y); qs[row][c4+2] = bf2f(u.z); qs[row][c4+3] = bf2f(u.w);
    float4 v = *reinterpret_cast<const float4*>(KVt + ((size_t)bhi << 12) + (row << 6) + c4);
    kvs[c4+0][row] = v.x; kvs[c4+1][row] = v.y; kvs[c4+2][row] = v.z; kvs[c4+3][row] = v.w;
  }
  if(t < 64) ksl[t] = Ksum[((size_t)bhi << 6) + t];
  __syncthreads();
  if(t < 64){
    float s = 0.f;
    for(int d = 0; d < 64; d++) s = fmaf(qs[d][t], ksl[d], s);
    nrm[t] = fmaxf(s, 1e-6f);
  }
  __syncthreads();
  const int tr = t >> 4, tc = t & 15;
  float acc[4][4] = {};
#pragma unroll
  for(int kk = 0; kk < 64; kk++){
    const float4 a4 = *reinterpret_cast<const float4*>(&qs[kk][tr << 2]);
    const float4 b4 = *reinterpret_cast<const float4*>(&kvs[kk][tc << 2]);
    const float av_[4] = {a4.x, a4.y, a4.z, a4.w};
    const float bv_[4] = {b4.x, b4.y, b4.z, b4.w};
#pragma unroll
    for(int i = 0; i < 4; i++)
#pragma unroll
      for(int j = 0; j < 4; j++) acc[i][j] = fmaf(av_[i], bv_[j], acc[i][j]);
  }
#pragma unroll
  for(int i = 0; i < 4; i++){
    const int gn = n0 + (tr << 2) + i;
    const float inv = 1.f / nrm[(tr << 2) + i];
    const size_t oi = (((size_t)b << 12) + gn) * 512 + h * 64 + (tc << 2);
    float4 p = *reinterpret_cast<const float4*>(mid + oi);
    p.x = fmaf(acc[i][0], inv, p.x);
    p.y = fmaf(acc[i][1], inv, p.y);
    p.z = fmaf(acc[i][2], inv, p.z);
    p.w = fmaf(acc[i][3], inv, p.w);
    ushort4 o = {f2bf(p.x), f2bf(p.y), f2bf(p.z), f2bf(p.w)};
    *reinterpret_cast<ushort4*>(midb + oi) = o;
  }
}

// ---------------- final GEMM: out(fp32) = midb(32768x512) @ Wo^T(512x512) ----------------
__global__ __launch_bounds__(256) void final_gemm(const u16* __restrict__ Am, const u16* __restrict__ Bm,
                                                  float* __restrict__ C){
  __shared__ u16 As[128 * 32];
  __shared__ u16 Bs[128 * 32];
  const int t = threadIdx.x;
  const int wid = t >> 6, lane = t & 63;
  const int wr = wid >> 1, wc = wid & 1;
  const int bm = blockIdx.x << 7, bn = blockIdx.y << 7;
  f32x4 acc[4][4];
#pragma unroll
  for(int m = 0; m < 4; m++)
#pragma unroll
    for(int n = 0; n < 4; n++) acc[m][n] = f32x4{0.f, 0.f, 0.f, 0.f};
  const int frow = lane & 15;
  const int kg8  = (lane >> 4) << 3;
  const int c0 = t, c1 = t + 256;
  for(int k0 = 0; k0 < 512; k0 += 32){
    GLD16(Am + (size_t)(bm + (c0 >> 2)) * 512 + k0 + ((c0 & 3) << 3), ((char*)As) + (wid << 10));
    GLD16(Am + (size_t)(bm + (c1 >> 2)) * 512 + k0 + ((c1 & 3) << 3), ((char*)As) + 4096 + (wid << 10));
    GLD16(Bm + (size_t)(bn + (c0 >> 2)) * 512 + k0 + ((c0 & 3) << 3), ((char*)Bs) + (wid << 10));
    GLD16(Bm + (size_t)(bn + (c1 >> 2)) * 512 + k0 + ((c1 & 3) << 3), ((char*)Bs) + 4096 + (wid << 10));
    __syncthreads();
    short8 af[4], bfr[4];
#pragma unroll
    for(int m = 0; m < 4; m++){
      af[m]  = *reinterpret_cast<const short8*>(As + (((wr << 6) + (m << 4) + frow) << 5) + kg8);
      bfr[m] = *reinterpret_cast<const short8*>(Bs + (((wc << 6) + (m << 4) + frow) << 5) + kg8);
    }
#pragma unroll
    for(int m = 0; m < 4; m++)
#pragma unroll
      for(int n = 0; n < 4; n++)
        acc[m][n] = __builtin_amdgcn_mfma_f32_16x16x32_bf16(af[m], bfr[n], acc[m][n], 0, 0, 0);
    __syncthreads();
  }
  const int cn = lane & 15, rb4 = (lane >> 4) << 2;
#pragma unroll
  for(int m = 0; m < 4; m++){
    const int row0 = bm + (wr << 6) + (m << 4) + rb4;
#pragma unroll
    for(int n = 0; n < 4; n++){
      const int col = bn + (wc << 6) + (n << 4) + cn;
#pragma unroll
      for(int j = 0; j < 4; j++)
        C[(size_t)(row0 + j) * 512 + col] = acc[m][n][j];
    }
  }
}

extern "C" void kernel_launch(void* const* d_in, const int* in_sizes, int n_in,
                              void* d_out, int out_size, void* d_ws, size_t ws_size,
                              hipStream_t stream){
  const float* x    = (const float*)d_in[0];
  const float* gb   = (const float*)d_in[1];
  const float* w_qd = (const float*)d_in[2];
  const float* w_qu = (const float*)d_in[3];
  const float* w_kd = (const float*)d_in[4];
  const float* w_ku = (const float*)d_in[5];
  const float* w_vd = (const float*)d_in[6];
  const float* w_vu = (const float*)d_in[7];
  const float* w_od = (const float*)d_in[8];
  const float* w_ou = (const float*)d_in[9];
  float* out = (float*)d_out;
  char* ws = (char*)d_ws;

  // layout (bytes):
  u16*   xb   = (u16*)  (ws);                 // 33554432
  u16*   Kt   = (u16*)  (ws + 33554432);      // 33554432
  u16*   Wall = (u16*)  (ws + 67108864);      // 2097152 (Wq,Wk,Wv,Wo @ 262144-elem strides)
  u16*   Qt   = (u16*)  (ws + 69206016);      // 33554432
  u16*   Vt   = (u16*)  (ws + 102760448);     // 33554432
  u16*   attn = (u16*)  (ws + 136314880);     // 33554432
  float* KVt  = (float*)(ws + 169869312);     // 1048576
  float* Ksum = (float*)(ws + 170917888);     // 16384
  float* mid  = (float*)(ws);                 // 64MB, overlaps xb+Kt (dead by then)
  u16*   midb = (u16*)  (ws + 136314880);     // overlaps attn (dead by then)

  hipMemsetAsync(KVt, 0, 1048576 + 16384, stream);

  combine_w<<<dim3(8, 8), 256, 0, stream>>>(w_qu, w_qd, Wall);
  combine_w<<<dim3(8, 8), 256, 0, stream>>>(w_ku, w_kd, Wall + 262144);
  combine_w<<<dim3(8, 8), 256, 0, stream>>>(w_vu, w_vd, Wall + 2 * 262144);
  combine_w<<<dim3(8, 8), 256, 0, stream>>>(w_ou, w_od, Wall + 3 * 262144);

  cast_x<<<8192, 256, 0, stream>>>(x, xb);
  softmax_rows<<<4096, 256, 0, stream>>>(gb, attn);

  // QKV: one MFMA GEMM, epilogue fuses ELU+1, transposed stores, Ksum
  qkv_gemm<<<dim3(256, 12), 256, 0, stream>>>(xb, Wall, Qt, Kt, Vt, Ksum);

  kvt_kernel<<<dim3(64, 8), 256, 0, stream>>>(Kt, Vt, KVt);

  // bias branch -> mid (fp32); mid overlaps xb (dead after qkv) + Kt (dead after kvt)
  bias_gemm<<<dim3(32, 32), 256, 0, stream>>>(attn, Vt, mid);

  // linear attention: add + cast -> midb (overlaps attn, dead after bias_gemm)
  linattn<<<dim3(64, 64), 256, 0, stream>>>(Qt, KVt, Ksum, mid, midb);

  // final projection: out = midb @ Wo^T (fp32 out)
  final_gemm<<<dim3(256, 4), 256, 0, stream>>>(midb, Wall + 3 * 262144, out);
}

// Round 3
// 473.032 us; speedup vs baseline: 1.7420x; 1.3138x over previous
//
#include <hip/hip_runtime.h>

typedef unsigned short u16;
typedef __attribute__((ext_vector_type(8))) short short8;
typedef __attribute__((ext_vector_type(4))) float f32x4;

#define GLD16(g, l) __builtin_amdgcn_global_load_lds((const __attribute__((address_space(1))) void*)(g), (__attribute__((address_space(3))) void*)(l), 16, 0, 0)

__device__ __forceinline__ u16 f2bf(float f){
  unsigned x = __float_as_uint(f);
  return (u16)((x + 0x7FFFu + ((x >> 16) & 1u)) >> 16);
}
__device__ __forceinline__ float bf2f(u16 u){
  return __uint_as_float(((unsigned)u) << 16);
}

// ---------------- generic fp32 -> bf16 cast (count = grid*2048) ----------------
__global__ __launch_bounds__(256) void castf2b(const float* __restrict__ src, u16* __restrict__ dst){
  const size_t i = ((size_t)blockIdx.x * 256 + threadIdx.x) * 8;
  float4 a = *reinterpret_cast<const float4*>(src + i);
  float4 b = *reinterpret_cast<const float4*>(src + i + 4);
  ushort4 o0 = {f2bf(a.x), f2bf(a.y), f2bf(a.z), f2bf(a.w)};
  ushort4 o1 = {f2bf(b.x), f2bf(b.y), f2bf(b.z), f2bf(b.w)};
  *reinterpret_cast<ushort4*>(dst + i) = o0;
  *reinterpret_cast<ushort4*>(dst + i + 4) = o1;
}

// ---------------- cast w_vd (64x512) into 128x512 region with zero pad rows 64..127 ----------------
__global__ __launch_bounds__(256) void cast_pad(const float* __restrict__ src, u16* __restrict__ dst){
  const int i = blockIdx.x * 256 + threadIdx.x;     // 8192 threads
  const int e = i * 8;
  const int r = e >> 9;
  ushort4 o0 = {0,0,0,0}, o1 = {0,0,0,0};
  if(r < 64){
    float4 a = *reinterpret_cast<const float4*>(src + e);
    float4 b = *reinterpret_cast<const float4*>(src + e + 4);
    o0 = ushort4{f2bf(a.x), f2bf(a.y), f2bf(a.z), f2bf(a.w)};
    o1 = ushort4{f2bf(b.x), f2bf(b.y), f2bf(b.z), f2bf(b.w)};
  }
  *reinterpret_cast<ushort4*>(dst + e) = o0;
  *reinterpret_cast<ushort4*>(dst + e + 4) = o1;
}

// ---------------- softmax over graph_bias rows -> bf16 attn ----------------
__global__ __launch_bounds__(256) void softmax_rows(const float* __restrict__ gb,
                                                    u16* __restrict__ attn){
  const int row = blockIdx.x;
  const float* rp = gb + (size_t)row * 4096;
  u16* op = attn + (size_t)row * 4096;
  const int t = threadIdx.x;
  float4 v[4];
  float mx = -3.4e38f;
#pragma unroll
  for(int k = 0; k < 4; k++){
    v[k] = *reinterpret_cast<const float4*>(rp + k*1024 + t*4);
    mx = fmaxf(mx, fmaxf(fmaxf(v[k].x, v[k].y), fmaxf(v[k].z, v[k].w)));
  }
#pragma unroll
  for(int off = 32; off > 0; off >>= 1) mx = fmaxf(mx, __shfl_xor(mx, off, 64));
  __shared__ float sred[4];
  __shared__ float sred2[4];
  const int wid = t >> 6, lane = t & 63;
  if(lane == 0) sred[wid] = mx;
  __syncthreads();
  mx = fmaxf(fmaxf(sred[0], sred[1]), fmaxf(sred[2], sred[3]));
  float s = 0.f;
#pragma unroll
  for(int k = 0; k < 4; k++){
    v[k].x = __expf(v[k].x - mx); v[k].y = __expf(v[k].y - mx);
    v[k].z = __expf(v[k].z - mx); v[k].w = __expf(v[k].w - mx);
    s += v[k].x + v[k].y + v[k].z + v[k].w;
  }
#pragma unroll
  for(int off = 32; off > 0; off >>= 1) s += __shfl_xor(s, off, 64);
  if(lane == 0) sred2[wid] = s;
  __syncthreads();
  s = sred2[0] + sred2[1] + sred2[2] + sred2[3];
  const float inv = 1.f / s;
#pragma unroll
  for(int k = 0; k < 4; k++){
    ushort4 o;
    o.x = f2bf(v[k].x * inv); o.y = f2bf(v[k].y * inv);
    o.z = f2bf(v[k].z * inv); o.w = f2bf(v[k].w * inv);
    *reinterpret_cast<ushort4*>(op + k*1024 + t*4) = o;
  }
}

// ---------------- combine low-rank pair: W = wu(512x64) @ wd(64x512), bf16 out ----------------
__global__ __launch_bounds__(256) void combine_w(const float* __restrict__ wu,
                                                 const float* __restrict__ wd,
                                                 u16* __restrict__ dst){
  __shared__ float au[64][68];
  __shared__ float bd[64][68];
  const int t = threadIdx.x;
  const int o0 = blockIdx.x << 6, i0 = blockIdx.y << 6;
#pragma unroll
  for(int q = 0; q < 4; q++){
    const int row = (q << 4) + (t >> 4);
    const int c4  = (t & 15) << 2;
    float4 u = *reinterpret_cast<const float4*>(wu + (size_t)(o0 + row) * 64 + c4);
    au[c4+0][row] = u.x; au[c4+1][row] = u.y; au[c4+2][row] = u.z; au[c4+3][row] = u.w;
    float4 v = *reinterpret_cast<const float4*>(wd + (size_t)row * 512 + i0 + c4);
    bd[row][c4+0] = v.x; bd[row][c4+1] = v.y; bd[row][c4+2] = v.z; bd[row][c4+3] = v.w;
  }
  __syncthreads();
  const int tr = t >> 4, tc = t & 15;
  float acc[4][4] = {};
#pragma unroll
  for(int kk = 0; kk < 64; kk++){
    const float4 a4 = *reinterpret_cast<const float4*>(&au[kk][tr << 2]);
    const float4 b4 = *reinterpret_cast<const float4*>(&bd[kk][tc << 2]);
    const float av_[4] = {a4.x, a4.y, a4.z, a4.w};
    const float bv_[4] = {b4.x, b4.y, b4.z, b4.w};
#pragma unroll
    for(int i = 0; i < 4; i++)
#pragma unroll
      for(int j = 0; j < 4; j++) acc[i][j] = fmaf(av_[i], bv_[j], acc[i][j]);
  }
#pragma unroll
  for(int i = 0; i < 4; i++){
    ushort4 o;
    o.x = f2bf(acc[i][0]); o.y = f2bf(acc[i][1]); o.z = f2bf(acc[i][2]); o.w = f2bf(acc[i][3]);
    *reinterpret_cast<ushort4*>(dst + (size_t)(o0 + (tr << 2) + i) * 512 + i0 + (tc << 2)) = o;
  }
}

// ---------------- Wvo = 0.1 * w_od(64x512) @ w_vu(512x64), fp32, one block ----------------
__global__ __launch_bounds__(256) void wvo_kernel(const float* __restrict__ w_od,
                                                  const float* __restrict__ w_vu,
                                                  float* __restrict__ Wvo){
  __shared__ float As[16][68];   // [kk][l]
  __shared__ float Bs[16][68];   // [kk][j]
  const int t = threadIdx.x;
  const int tr = t >> 4, tc = t & 15;
  float acc[4][4] = {};
  for(int k0 = 0; k0 < 512; k0 += 16){
    __syncthreads();
#pragma unroll
    for(int q = 0; q < 4; q++){
      const int idx = q * 256 + t;
      const int kk = idx >> 6, l = idx & 63;
      As[kk][l] = w_od[(size_t)l * 512 + k0 + kk];
      Bs[kk][l] = w_vu[(size_t)(k0 + kk) * 64 + l];
    }
    __syncthreads();
#pragma unroll
    for(int kk = 0; kk < 16; kk++){
      const float4 a4 = *reinterpret_cast<const float4*>(&As[kk][tr << 2]);
      const float4 b4 = *reinterpret_cast<const float4*>(&Bs[kk][tc << 2]);
      const float av_[4] = {a4.x, a4.y, a4.z, a4.w};
      const float bv_[4] = {b4.x, b4.y, b4.z, b4.w};
#pragma unroll
      for(int i = 0; i < 4; i++)
#pragma unroll
        for(int j = 0; j < 4; j++) acc[i][j] = fmaf(av_[i], bv_[j], acc[i][j]);
    }
  }
#pragma unroll
  for(int i = 0; i < 4; i++)
#pragma unroll
    for(int j = 0; j < 4; j++)
      Wvo[(size_t)((tr << 2) + i) * 64 + (tc << 2) + j] = 0.1f * acc[i][j];
}

// ---------------- QK+Vlow GEMM: C = xb(32768x512) @ Wall^T(1152x512) ----------------
// cols 0..511 Q (ELU+1, store Qt[bh][d][n]); 512..1023 K (ELU+1, Kt + Ksum);
// 1024..1087 Vlow (plain, store Vlowt[b*64+j][n]); 1088..1151 pad (skip).
__global__ __launch_bounds__(256) void qkvlow_gemm(const u16* __restrict__ Am, const u16* __restrict__ Bm,
                                                   u16* __restrict__ Qt, u16* __restrict__ Kt,
                                                   u16* __restrict__ Vlowt, float* __restrict__ Ksum){
  __shared__ u16 As[128 * 32];
  __shared__ u16 Bs[128 * 32];
  const int t = threadIdx.x;
  const int wid = t >> 6, lane = t & 63;
  const int wr = wid >> 1, wc = wid & 1;
  const int bm = blockIdx.x << 7, bn = blockIdx.y << 7;
  f32x4 acc[4][4];
#pragma unroll
  for(int m = 0; m < 4; m++)
#pragma unroll
    for(int n = 0; n < 4; n++) acc[m][n] = f32x4{0.f, 0.f, 0.f, 0.f};
  const int frow = lane & 15;
  const int kg8  = (lane >> 4) << 3;
  const int c0 = t, c1 = t + 256;
  for(int k0 = 0; k0 < 512; k0 += 32){
    GLD16(Am + (size_t)(bm + (c0 >> 2)) * 512 + k0 + ((c0 & 3) << 3), ((char*)As) + (wid << 10));
    GLD16(Am + (size_t)(bm + (c1 >> 2)) * 512 + k0 + ((c1 & 3) << 3), ((char*)As) + 4096 + (wid << 10));
    GLD16(Bm + (size_t)(bn + (c0 >> 2)) * 512 + k0 + ((c0 & 3) << 3), ((char*)Bs) + (wid << 10));
    GLD16(Bm + (size_t)(bn + (c1 >> 2)) * 512 + k0 + ((c1 & 3) << 3), ((char*)Bs) + 4096 + (wid << 10));
    __syncthreads();
    short8 af[4], bfr[4];
#pragma unroll
    for(int m = 0; m < 4; m++){
      af[m]  = *reinterpret_cast<const short8*>(As + (((wr << 6) + (m << 4) + frow) << 5) + kg8);
      bfr[m] = *reinterpret_cast<const short8*>(Bs + (((wc << 6) + (m << 4) + frow) << 5) + kg8);
    }
#pragma unroll
    for(int m = 0; m < 4; m++)
#pragma unroll
      for(int n = 0; n < 4; n++)
        acc[m][n] = __builtin_amdgcn_mfma_f32_16x16x32_bf16(af[m], bfr[n], acc[m][n], 0, 0, 0);
    __syncthreads();
  }
  const int cn = lane & 15, rb4 = (lane >> 4) << 2;
  const int b = bm >> 12;
#pragma unroll
  for(int nf = 0; nf < 4; nf++){
    const int col = bn + (wc << 6) + (nf << 4) + cn;
    u16* rowp;
    bool isK = false, isQorK = false;
    if(col < 512){
      rowp = Qt + ((((size_t)((b << 3) + (col >> 6)) << 6) + (col & 63)) << 12);
      isQorK = true;
    } else if(col < 1024){
      const int c = col - 512;
      rowp = Kt + ((((size_t)((b << 3) + (c >> 6)) << 6) + (c & 63)) << 12);
      isK = true; isQorK = true;
    } else {
      const int j = col - 1024;
      if(j >= 64) continue;
      rowp = Vlowt + ((size_t)((b << 6) + j) << 12);
    }
    float ks = 0.f;
#pragma unroll
    for(int mf = 0; mf < 4; mf++){
      const int nn0 = (bm & 4095) + (wr << 6) + (mf << 4) + rb4;
      float v0 = acc[mf][nf][0], v1 = acc[mf][nf][1], v2 = acc[mf][nf][2], v3 = acc[mf][nf][3];
      if(isQorK){
        v0 = v0 > 0.f ? v0 + 1.f : __expf(v0);
        v1 = v1 > 0.f ? v1 + 1.f : __expf(v1);
        v2 = v2 > 0.f ? v2 + 1.f : __expf(v2);
        v3 = v3 > 0.f ? v3 + 1.f : __expf(v3);
      }
      if(isK) ks += v0 + v1 + v2 + v3;
      ushort4 o = {f2bf(v0), f2bf(v1), f2bf(v2), f2bf(v3)};
      *reinterpret_cast<ushort4*>(rowp + nn0) = o;
    }
    if(isK){
      ks += __shfl_xor(ks, 16);
      ks += __shfl_xor(ks, 32);
      if(lane < 16){
        const int c = col - 512;
        atomicAdd(Ksum + ((size_t)((b << 3) + (c >> 6)) << 6) + (c & 63), ks);
      }
    }
  }
}

// ---------------- KVlow[bh][d][j] = sum_n Kt[bh,d,n] * Vlowt[b*64+j,n]; split-n atomics ----------------
__global__ __launch_bounds__(256) void kvlow_gemm(const u16* __restrict__ Kt,
                                                  const u16* __restrict__ Vlowt,
                                                  float* __restrict__ KVlow){
  __shared__ u16 As[64 * 32];
  __shared__ u16 Bs[64 * 32];
  const int bh = blockIdx.x, sp = blockIdx.y;
  const int b = bh >> 3;
  const int t = threadIdx.x;
  const int wid = t >> 6, lane = t & 63;
  const int frow = lane & 15, kg8 = (lane >> 4) << 3;
  const size_t kbase = (size_t)bh << 18;
  const size_t vbase = (size_t)b << 18;
  const int srow = t >> 2, soff = (t & 3) << 3;
  f32x4 acc[4];
#pragma unroll
  for(int n = 0; n < 4; n++) acc[n] = f32x4{0.f, 0.f, 0.f, 0.f};
  const int nend = (sp << 10) + 1024;
  for(int n0 = sp << 10; n0 < nend; n0 += 32){
    GLD16(Kt    + kbase + ((size_t)srow << 12) + n0 + soff, ((char*)As) + (wid << 10));
    GLD16(Vlowt + vbase + ((size_t)srow << 12) + n0 + soff, ((char*)Bs) + (wid << 10));
    __syncthreads();
    short8 af = *reinterpret_cast<const short8*>(As + (((wid << 4) + frow) << 5) + kg8);
#pragma unroll
    for(int n = 0; n < 4; n++){
      short8 bf8 = *reinterpret_cast<const short8*>(Bs + (((n << 4) + frow) << 5) + kg8);
      acc[n] = __builtin_amdgcn_mfma_f32_16x16x32_bf16(af, bf8, acc[n], 0, 0, 0);
    }
    __syncthreads();
  }
  const int cn = lane & 15, rb4 = (lane >> 4) << 2;
#pragma unroll
  for(int n = 0; n < 4; n++)
#pragma unroll
    for(int j = 0; j < 4; j++){
      const int d = (wid << 4) + rb4 + j;
      const int jj = (n << 4) + cn;
      atomicAdd(KVlow + ((size_t)bh << 12) + (size_t)d * 64 + jj, acc[n][j]);
    }
}

// ---------------- KVt[bh][hd][d] = sum_j KVlow[bh][d][j] * w_vu[h*64+hd][j] ----------------
__global__ __launch_bounds__(256) void kv_apply(const float* __restrict__ KVlow,
                                                const float* __restrict__ w_vu,
                                                float* __restrict__ KVt){
  __shared__ float Kl[64][68];   // [j][d]
  __shared__ float Wl[64][68];   // [j][hd]
  const int bh = blockIdx.x, h = bh & 7;
  const int t = threadIdx.x;
#pragma unroll
  for(int q = 0; q < 4; q++){
    const int row = (q << 4) + (t >> 4);
    const int c4  = (t & 15) << 2;
    float4 v = *reinterpret_cast<const float4*>(KVlow + ((size_t)bh << 12) + (size_t)row * 64 + c4);
    Kl[c4+0][row] = v.x; Kl[c4+1][row] = v.y; Kl[c4+2][row] = v.z; Kl[c4+3][row] = v.w;
    float4 w = *reinterpret_cast<const float4*>(w_vu + (size_t)((h << 6) + row) * 64 + c4);
    Wl[c4+0][row] = w.x; Wl[c4+1][row] = w.y; Wl[c4+2][row] = w.z; Wl[c4+3][row] = w.w;
  }
  __syncthreads();
  const int tr = t >> 4, tc = t & 15;
  float acc[4][4] = {};
#pragma unroll
  for(int kk = 0; kk < 64; kk++){
    const float4 a4 = *reinterpret_cast<const float4*>(&Wl[kk][tr << 2]);
    const float4 b4 = *reinterpret_cast<const float4*>(&Kl[kk][tc << 2]);
    const float av_[4] = {a4.x, a4.y, a4.z, a4.w};
    const float bv_[4] = {b4.x, b4.y, b4.z, b4.w};
#pragma unroll
    for(int i = 0; i < 4; i++)
#pragma unroll
      for(int j = 0; j < 4; j++) acc[i][j] = fmaf(av_[i], bv_[j], acc[i][j]);
  }
#pragma unroll
  for(int i = 0; i < 4; i++){
    float4 o = {acc[i][0], acc[i][1], acc[i][2], acc[i][3]};
    *reinterpret_cast<float4*>(KVt + ((size_t)bh << 12) + (size_t)((tr << 2) + i) * 64 + (tc << 2)) = o;
  }
}

// ---------------- bias_pv: Pv[kz][i][c] = sum_{k in half kz} attn[i,k] * Vlowt[c,k] ----------------
__global__ __launch_bounds__(256) void bias_pv(const u16* __restrict__ Am,
                                               const u16* __restrict__ Bm,
                                               float* __restrict__ Pv){
  __shared__ u16 As[128 * 32];
  __shared__ u16 Bs[128 * 32];
  const int t = threadIdx.x;
  const int wid = t >> 6, lane = t & 63;
  const int wr = wid >> 1, wc = wid & 1;
  const int bm = blockIdx.x << 7, bn = blockIdx.y << 7, kz = blockIdx.z;
  f32x4 acc[4][4];
#pragma unroll
  for(int m = 0; m < 4; m++)
#pragma unroll
    for(int n = 0; n < 4; n++) acc[m][n] = f32x4{0.f, 0.f, 0.f, 0.f};
  const int frow = lane & 15;
  const int kg8  = (lane >> 4) << 3;
  const int c0 = t, c1 = t + 256;
  const int kend = (kz << 11) + 2048;
  for(int k0 = kz << 11; k0 < kend; k0 += 32){
    GLD16(Am + ((size_t)(bm + (c0 >> 2)) << 12) + k0 + ((c0 & 3) << 3), ((char*)As) + (wid << 10));
    GLD16(Am + ((size_t)(bm + (c1 >> 2)) << 12) + k0 + ((c1 & 3) << 3), ((char*)As) + 4096 + (wid << 10));
    GLD16(Bm + ((size_t)(bn + (c0 >> 2)) << 12) + k0 + ((c0 & 3) << 3), ((char*)Bs) + (wid << 10));
    GLD16(Bm + ((size_t)(bn + (c1 >> 2)) << 12) + k0 + ((c1 & 3) << 3), ((char*)Bs) + 4096 + (wid << 10));
    __syncthreads();
    short8 af[4], bfr[4];
#pragma unroll
    for(int m = 0; m < 4; m++){
      af[m]  = *reinterpret_cast<const short8*>(As + (((wr << 6) + (m << 4) + frow) << 5) + kg8);
      bfr[m] = *reinterpret_cast<const short8*>(Bs + (((wc << 6) + (m << 4) + frow) << 5) + kg8);
    }
#pragma unroll
    for(int m = 0; m < 4; m++)
#pragma unroll
      for(int n = 0; n < 4; n++)
        acc[m][n] = __builtin_amdgcn_mfma_f32_16x16x32_bf16(af[m], bfr[n], acc[m][n], 0, 0, 0);
    __syncthreads();
  }
  const int cn = lane & 15, rb4 = (lane >> 4) << 2;
  float* P = Pv + (size_t)kz * 2097152;
#pragma unroll
  for(int m = 0; m < 4; m++){
    const int row0 = bm + (wr << 6) + (m << 4) + rb4;
#pragma unroll
    for(int n = 0; n < 4; n++){
      const int col = bn + (wc << 6) + (n << 4) + cn;
#pragma unroll
      for(int j = 0; j < 4; j++)
        P[(size_t)(row0 + j) * 512 + col] = acc[m][n][j];
    }
  }
}

// ---------------- linear attention: midb = bf16( (Q @ KVt^T)/clip(Q.Ksum) ) ----------------
__global__ __launch_bounds__(256) void linattn(const u16* __restrict__ Qt,
                                               const float* __restrict__ KVt,
                                               const float* __restrict__ Ksum,
                                               u16* __restrict__ midb){
  __shared__ float qs[64][64];
  __shared__ float kvs[64][64];
  __shared__ float nrm[64];
  __shared__ float ksl[64];
  const int nblk = blockIdx.x, bhi = blockIdx.y;
  const int b = bhi >> 3, h = bhi & 7;
  const int n0 = nblk << 6;
  const int t = threadIdx.x;
#pragma unroll
  for(int q = 0; q < 4; q++){
    const int row = (q << 4) + (t >> 4);
    const int c4  = (t & 15) << 2;
    ushort4 u = *reinterpret_cast<const ushort4*>(Qt + ((((size_t)bhi << 6) + row) << 12) + n0 + c4);
    qs[row][c4+0] = bf2f(u.x); qs[row][c4+1] = bf2f(u.y); qs[row][c4+2] = bf2f(u.z); qs[row][c4+3] = bf2f(u.w);
    float4 v = *reinterpret_cast<const float4*>(KVt + ((size_t)bhi << 12) + (row << 6) + c4);
    kvs[c4+0][row] = v.x; kvs[c4+1][row] = v.y; kvs[c4+2][row] = v.z; kvs[c4+3][row] = v.w;
  }
  if(t < 64) ksl[t] = Ksum[((size_t)bhi << 6) + t];
  __syncthreads();
  if(t < 64){
    float s = 0.f;
    for(int d = 0; d < 64; d++) s = fmaf(qs[d][t], ksl[d], s);
    nrm[t] = fmaxf(s, 1e-6f);
  }
  __syncthreads();
  const int tr = t >> 4, tc = t & 15;
  float acc[4][4] = {};
#pragma unroll
  for(int kk = 0; kk < 64; kk++){
    const float4 a4 = *reinterpret_cast<const float4*>(&qs[kk][tr << 2]);
    const float4 b4 = *reinterpret_cast<const float4*>(&kvs[kk][tc << 2]);
    const float av_[4] = {a4.x, a4.y, a4.z, a4.w};
    const float bv_[4] = {b4.x, b4.y, b4.z, b4.w};
#pragma unroll
    for(int i = 0; i < 4; i++)
#pragma unroll
      for(int j = 0; j < 4; j++) acc[i][j] = fmaf(av_[i], bv_[j], acc[i][j]);
  }
#pragma unroll
  for(int i = 0; i < 4; i++){
    const int gn = n0 + (tr << 2) + i;
    const float inv = 1.f / nrm[(tr << 2) + i];
    const size_t oi = (((size_t)b << 12) + gn) * 512 + h * 64 + (tc << 2);
    ushort4 o = {f2bf(acc[i][0] * inv), f2bf(acc[i][1] * inv),
                 f2bf(acc[i][2] * inv), f2bf(acc[i][3] * inv)};
    *reinterpret_cast<ushort4*>(midb + oi) = o;
  }
}

// ---------------- biaslow: G[(b,n)][l] = sum_j (Pv0+Pv1)[n][b*64+j] * Wvo[l][j] ----------------
__global__ __launch_bounds__(256) void biaslow(const float* __restrict__ Pv,
                                               const float* __restrict__ Wvo,
                                               float* __restrict__ G){
  __shared__ float Pl[64][68];   // [j][n]
  __shared__ float Wl[64][68];   // [j][l]
  const int nt = blockIdx.x, b = blockIdx.y;
  const int n0 = nt << 6;
  const int t = threadIdx.x;
#pragma unroll
  for(int q = 0; q < 4; q++){
    const int row = (q << 4) + (t >> 4);
    const int c4  = (t & 15) << 2;
    float4 v  = *reinterpret_cast<const float4*>(Pv + (size_t)(n0 + row) * 512 + (b << 6) + c4);
    float4 v2 = *reinterpret_cast<const float4*>(Pv + 2097152 + (size_t)(n0 + row) * 512 + (b << 6) + c4);
    Pl[c4+0][row] = v.x + v2.x; Pl[c4+1][row] = v.y + v2.y;
    Pl[c4+2][row] = v.z + v2.z; Pl[c4+3][row] = v.w + v2.w;
    float4 w = *reinterpret_cast<const float4*>(Wvo + (size_t)row * 64 + c4);
    Wl[c4+0][row] = w.x; Wl[c4+1][row] = w.y; Wl[c4+2][row] = w.z; Wl[c4+3][row] = w.w;
  }
  __syncthreads();
  const int tr = t >> 4, tc = t & 15;
  float acc[4][4] = {};
#pragma unroll
  for(int kk = 0; kk < 64; kk++){
    const float4 a4 = *reinterpret_cast<const float4*>(&Pl[kk][tr << 2]);
    const float4 b4 = *reinterpret_cast<const float4*>(&Wl[kk][tc << 2]);
    const float av_[4] = {a4.x, a4.y, a4.z, a4.w};
    const float bv_[4] = {b4.x, b4.y, b4.z, b4.w};
#pragma unroll
    for(int i = 0; i < 4; i++)
#pragma unroll
      for(int j = 0; j < 4; j++) acc[i][j] = fmaf(av_[i], bv_[j], acc[i][j]);
  }
#pragma unroll
  for(int i = 0; i < 4; i++){
    float4 o = {acc[i][0], acc[i][1], acc[i][2], acc[i][3]};
    *reinterpret_cast<float4*>(G + (size_t)(((size_t)b << 12) + n0 + (tr << 2) + i) * 64 + (tc << 2)) = o;
  }
}

// ---------------- down_gemm: Gb = bf16( midb(32768x512) @ wodb^T(64x512) + G ) ----------------
__global__ __launch_bounds__(256) void down_gemm(const u16* __restrict__ Am,
                                                 const u16* __restrict__ Bw,
                                                 const float* __restrict__ Gin,
                                                 u16* __restrict__ Gb){
  __shared__ u16 As[128 * 32];
  const int t = threadIdx.x;
  const int wid = t >> 6, lane = t & 63;
  const int bm = blockIdx.x << 7;
  const int frow = lane & 15, kg8 = (lane >> 4) << 3;
  f32x4 acc[2][4];
#pragma unroll
  for(int m = 0; m < 2; m++)
#pragma unroll
    for(int n = 0; n < 4; n++) acc[m][n] = f32x4{0.f, 0.f, 0.f, 0.f};
  const int c0 = t, c1 = t + 256;
  for(int k0 = 0; k0 < 512; k0 += 32){
    GLD16(Am + (size_t)(bm + (c0 >> 2)) * 512 + k0 + ((c0 & 3) << 3), ((char*)As) + (wid << 10));
    GLD16(Am + (size_t)(bm + (c1 >> 2)) * 512 + k0 + ((c1 & 3) << 3), ((char*)As) + 4096 + (wid << 10));
    __syncthreads();
    short8 af[2], bfr[4];
#pragma unroll
    for(int m = 0; m < 2; m++)
      af[m] = *reinterpret_cast<const short8*>(As + (((wid << 5) + (m << 4) + frow) << 5) + kg8);
#pragma unroll
    for(int n = 0; n < 4; n++)
      bfr[n] = *reinterpret_cast<const short8*>(Bw + (size_t)((n << 4) + frow) * 512 + k0 + kg8);
#pragma unroll
    for(int m = 0; m < 2; m++)
#pragma unroll
      for(int n = 0; n < 4; n++)
        acc[m][n] = __builtin_amdgcn_mfma_f32_16x16x32_bf16(af[m], bfr[n], acc[m][n], 0, 0, 0);
    __syncthreads();
  }
  const int cn = lane & 15, rb4 = (lane >> 4) << 2;
#pragma unroll
  for(int m = 0; m < 2; m++){
#pragma unroll
    for(int n = 0; n < 4; n++){
      const int col = (n << 4) + cn;
#pragma unroll
      for(int j = 0; j < 4; j++){
        const int r = bm + (wid << 5) + (m << 4) + rb4 + j;
        const float v = acc[m][n][j] + Gin[(size_t)r * 64 + col];
        Gb[(size_t)r * 64 + col] = f2bf(v);
      }
    }
  }
}

// ---------------- up_gemm: out(fp32 32768x512) = Gb(32768x64) @ woub^T(512x64); no LDS ----------------
__global__ __launch_bounds__(256) void up_gemm(const u16* __restrict__ Am,
                                               const u16* __restrict__ Bw,
                                               float* __restrict__ C){
  const int t = threadIdx.x;
  const int wid = t >> 6, lane = t & 63;
  const int wr = wid >> 1, wc = wid & 1;
  const int bm = blockIdx.x << 7, bn = blockIdx.y << 7;
  const int frow = lane & 15, kg8 = (lane >> 4) << 3;
  f32x4 acc[4][4];
#pragma unroll
  for(int m = 0; m < 4; m++)
#pragma unroll
    for(int n = 0; n < 4; n++) acc[m][n] = f32x4{0.f, 0.f, 0.f, 0.f};
  short8 af[4][2], bfr[4][2];
#pragma unroll
  for(int m = 0; m < 4; m++)
#pragma unroll
    for(int kk = 0; kk < 2; kk++)
      af[m][kk] = *reinterpret_cast<const short8*>(Am + (size_t)(bm + (wr << 6) + (m << 4) + frow) * 64 + (kk << 5) + kg8);
#pragma unroll
  for(int n = 0; n < 4; n++)
#pragma unroll
    for(int kk = 0; kk < 2; kk++)
      bfr[n][kk] = *reinterpret_cast<const short8*>(Bw + (size_t)(bn + (wc << 6) + (n << 4) + frow) * 64 + (kk << 5) + kg8);
#pragma unroll
  for(int m = 0; m < 4; m++)
#pragma unroll
    for(int n = 0; n < 4; n++){
      acc[m][n] = __builtin_amdgcn_mfma_f32_16x16x32_bf16(af[m][0], bfr[n][0], acc[m][n], 0, 0, 0);
      acc[m][n] = __builtin_amdgcn_mfma_f32_16x16x32_bf16(af[m][1], bfr[n][1], acc[m][n], 0, 0, 0);
    }
  const int cn = lane & 15, rb4 = (lane >> 4) << 2;
#pragma unroll
  for(int m = 0; m < 4; m++){
    const int row0 = bm + (wr << 6) + (m << 4) + rb4;
#pragma unroll
    for(int n = 0; n < 4; n++){
      const int col = bn + (wc << 6) + (n << 4) + cn;
#pragma unroll
      for(int j = 0; j < 4; j++)
        C[(size_t)(row0 + j) * 512 + col] = acc[m][n][j];
    }
  }
}

extern "C" void kernel_launch(void* const* d_in, const int* in_sizes, int n_in,
                              void* d_out, int out_size, void* d_ws, size_t ws_size,
                              hipStream_t stream){
  const float* x    = (const float*)d_in[0];
  const float* gb   = (const float*)d_in[1];
  const float* w_qd = (const float*)d_in[2];
  const float* w_qu = (const float*)d_in[3];
  const float* w_kd = (const float*)d_in[4];
  const float* w_ku = (const float*)d_in[5];
  const float* w_vd = (const float*)d_in[6];
  const float* w_vu = (const float*)d_in[7];
  const float* w_od = (const float*)d_in[8];
  const float* w_ou = (const float*)d_in[9];
  float* out = (float*)d_out;
  char* ws = (char*)d_ws;

  u16*   xb    = (u16*)  (ws);                  // 33554432
  u16*   Kt    = (u16*)  (ws + 33554432);       // 33554432
  u16*   Wall  = (u16*)  (ws + 67108864);       // 1152*512*2 = 1179648
  u16*   wodb  = (u16*)  (ws + 68288512);       // 65536
  u16*   woub  = (u16*)  (ws + 68354048);       // 65536
  float* Wvo   = (float*)(ws + 68419584);       // 16384
  u16*   Qt    = (u16*)  (ws + 68435968);       // 33554432
  u16*   Vlowt = (u16*)  (ws + 101990400);      // 4194304
  u16*   attn  = (u16*)  (ws + 106184704);      // 33554432
  float* Pv    = (float*)(ws + 139739136);      // 2 x 8388608
  float* KVlow = (float*)(ws + 156516352);      // 1048576
  float* KVt   = (float*)(ws + 157564928);      // 1048576
  float* Ksum  = (float*)(ws + 158613504);      // 16384
  u16*   midb  = (u16*)  (ws);                  // overlaps xb (dead after qkvlow_gemm)
  float* G     = (float*)(ws + 33554432);       // overlaps Kt (dead after kvlow_gemm)
  u16*   Gb    = (u16*)  (ws + 41943040);       // within old Kt

  // zero KVlow (+KVt harmless) + Ksum (atomic targets)
  hipMemsetAsync(KVlow, 0, 2113536, stream);

  // weight prep
  combine_w<<<dim3(8, 8), 256, 0, stream>>>(w_qu, w_qd, Wall);
  combine_w<<<dim3(8, 8), 256, 0, stream>>>(w_ku, w_kd, Wall + 262144);
  cast_pad<<<32, 256, 0, stream>>>(w_vd, Wall + 524288);
  castf2b<<<16, 256, 0, stream>>>(w_od, wodb);
  castf2b<<<16, 256, 0, stream>>>(w_ou, woub);
  wvo_kernel<<<1, 256, 0, stream>>>(w_od, w_vu, Wvo);

  castf2b<<<8192, 256, 0, stream>>>(x, xb);
  softmax_rows<<<4096, 256, 0, stream>>>(gb, attn);

  // Q, K (ELU+1, transposed) + Vlow (transposed) in one MFMA GEMM
  qkvlow_gemm<<<dim3(256, 9), 256, 0, stream>>>(xb, Wall, Qt, Kt, Vlowt, Ksum);

  // KVlow = K^T @ Vlow per head (split-n atomics), then apply w_vu -> KVt
  kvlow_gemm<<<dim3(64, 4), 256, 0, stream>>>(Kt, Vlowt, KVlow);
  kv_apply<<<64, 256, 0, stream>>>(KVlow, w_vu, KVt);

  // bias branch in low-rank space: Pv = attn @ Vlowt^T (split-K=2)
  bias_pv<<<dim3(32, 4, 2), 256, 0, stream>>>(attn, Vlowt, Pv);

  // linear attention -> midb (bf16)
  linattn<<<dim3(64, 64), 256, 0, stream>>>(Qt, KVt, Ksum, midb);

  // bias contribution in rank-64 space -> G
  biaslow<<<dim3(64, 8), 256, 0, stream>>>(Pv, Wvo, G);

  // down: Gb = bf16(midb @ wodb^T + G)
  down_gemm<<<256, 256, 0, stream>>>(midb, wodb, G, Gb);

  // up: out = Gb @ woub^T
  up_gemm<<<dim3(256, 4), 256, 0, stream>>>(Gb, woub, out);
}

// Round 4
// 452.719 us; speedup vs baseline: 1.8201x; 1.0449x over previous
//
#include <hip/hip_runtime.h>

typedef unsigned short u16;
typedef __attribute__((ext_vector_type(8))) short short8;
typedef __attribute__((ext_vector_type(4))) float f32x4;

#define GLD16(g, l) __builtin_amdgcn_global_load_lds((const __attribute__((address_space(1))) void*)(g), (__attribute__((address_space(3))) void*)(l), 16, 0, 0)

__device__ __forceinline__ u16 f2bf(float f){
  unsigned x = __float_as_uint(f);
  return (u16)((x + 0x7FFFu + ((x >> 16) & 1u)) >> 16);
}
__device__ __forceinline__ float bf2f(u16 u){
  return __uint_as_float(((unsigned)u) << 16);
}

// ---------------- merged small weight prep: wod->bf16, wou->bf16, wvd->bf16 padded ----------------
__global__ __launch_bounds__(256) void prep_w(const float* __restrict__ w_od,
                                              const float* __restrict__ w_ou,
                                              const float* __restrict__ w_vd,
                                              u16* __restrict__ wodb,
                                              u16* __restrict__ woub,
                                              u16* __restrict__ wpad){
  const int bid = blockIdx.x, t = threadIdx.x;
  if(bid < 16){
    const size_t i = ((size_t)bid * 256 + t) * 8;
    float4 a = *reinterpret_cast<const float4*>(w_od + i);
    float4 b = *reinterpret_cast<const float4*>(w_od + i + 4);
    ushort4 o0 = {f2bf(a.x), f2bf(a.y), f2bf(a.z), f2bf(a.w)};
    ushort4 o1 = {f2bf(b.x), f2bf(b.y), f2bf(b.z), f2bf(b.w)};
    *reinterpret_cast<ushort4*>(wodb + i) = o0;
    *reinterpret_cast<ushort4*>(wodb + i + 4) = o1;
  } else if(bid < 32){
    const size_t i = ((size_t)(bid - 16) * 256 + t) * 8;
    float4 a = *reinterpret_cast<const float4*>(w_ou + i);
    float4 b = *reinterpret_cast<const float4*>(w_ou + i + 4);
    ushort4 o0 = {f2bf(a.x), f2bf(a.y), f2bf(a.z), f2bf(a.w)};
    ushort4 o1 = {f2bf(b.x), f2bf(b.y), f2bf(b.z), f2bf(b.w)};
    *reinterpret_cast<ushort4*>(woub + i) = o0;
    *reinterpret_cast<ushort4*>(woub + i + 4) = o1;
  } else {
    const int i = (bid - 32) * 256 + t;
    const int e = i * 8;
    const int r = e >> 9;
    ushort4 o0 = {0,0,0,0}, o1 = {0,0,0,0};
    if(r < 64){
      float4 a = *reinterpret_cast<const float4*>(w_vd + e);
      float4 b = *reinterpret_cast<const float4*>(w_vd + e + 4);
      o0 = ushort4{f2bf(a.x), f2bf(a.y), f2bf(a.z), f2bf(a.w)};
      o1 = ushort4{f2bf(b.x), f2bf(b.y), f2bf(b.z), f2bf(b.w)};
    }
    *reinterpret_cast<ushort4*>(wpad + e) = o0;
    *reinterpret_cast<ushort4*>(wpad + e + 4) = o1;
  }
}

// ---------------- x fp32 -> bf16 ----------------
__global__ __launch_bounds__(256) void castf2b(const float* __restrict__ src, u16* __restrict__ dst){
  const size_t i = ((size_t)blockIdx.x * 256 + threadIdx.x) * 8;
  float4 a = *reinterpret_cast<const float4*>(src + i);
  float4 b = *reinterpret_cast<const float4*>(src + i + 4);
  ushort4 o0 = {f2bf(a.x), f2bf(a.y), f2bf(a.z), f2bf(a.w)};
  ushort4 o1 = {f2bf(b.x), f2bf(b.y), f2bf(b.z), f2bf(b.w)};
  *reinterpret_cast<ushort4*>(dst + i) = o0;
  *reinterpret_cast<ushort4*>(dst + i + 4) = o1;
}

// ---------------- softmax over graph_bias rows -> bf16 attn ----------------
__global__ __launch_bounds__(256) void softmax_rows(const float* __restrict__ gb,
                                                    u16* __restrict__ attn){
  const int row = blockIdx.x;
  const float* rp = gb + (size_t)row * 4096;
  u16* op = attn + (size_t)row * 4096;
  const int t = threadIdx.x;
  float4 v[4];
  float mx = -3.4e38f;
#pragma unroll
  for(int k = 0; k < 4; k++){
    v[k] = *reinterpret_cast<const float4*>(rp + k*1024 + t*4);
    mx = fmaxf(mx, fmaxf(fmaxf(v[k].x, v[k].y), fmaxf(v[k].z, v[k].w)));
  }
#pragma unroll
  for(int off = 32; off > 0; off >>= 1) mx = fmaxf(mx, __shfl_xor(mx, off, 64));
  __shared__ float sred[4];
  __shared__ float sred2[4];
  const int wid = t >> 6, lane = t & 63;
  if(lane == 0) sred[wid] = mx;
  __syncthreads();
  mx = fmaxf(fmaxf(sred[0], sred[1]), fmaxf(sred[2], sred[3]));
  float s = 0.f;
#pragma unroll
  for(int k = 0; k < 4; k++){
    v[k].x = __expf(v[k].x - mx); v[k].y = __expf(v[k].y - mx);
    v[k].z = __expf(v[k].z - mx); v[k].w = __expf(v[k].w - mx);
    s += v[k].x + v[k].y + v[k].z + v[k].w;
  }
#pragma unroll
  for(int off = 32; off > 0; off >>= 1) s += __shfl_xor(s, off, 64);
  if(lane == 0) sred2[wid] = s;
  __syncthreads();
  s = sred2[0] + sred2[1] + sred2[2] + sred2[3];
  const float inv = 1.f / s;
#pragma unroll
  for(int k = 0; k < 4; k++){
    ushort4 o;
    o.x = f2bf(v[k].x * inv); o.y = f2bf(v[k].y * inv);
    o.z = f2bf(v[k].z * inv); o.w = f2bf(v[k].w * inv);
    *reinterpret_cast<ushort4*>(op + k*1024 + t*4) = o;
  }
}

// ---------------- combine low-rank pair: W = wu(512x64) @ wd(64x512), bf16 out ----------------
__global__ __launch_bounds__(256) void combine_w(const float* __restrict__ wu,
                                                 const float* __restrict__ wd,
                                                 u16* __restrict__ dst){
  __shared__ float au[64][68];
  __shared__ float bd[64][68];
  const int t = threadIdx.x;
  const int o0 = blockIdx.x << 6, i0 = blockIdx.y << 6;
#pragma unroll
  for(int q = 0; q < 4; q++){
    const int row = (q << 4) + (t >> 4);
    const int c4  = (t & 15) << 2;
    float4 u = *reinterpret_cast<const float4*>(wu + (size_t)(o0 + row) * 64 + c4);
    au[c4+0][row] = u.x; au[c4+1][row] = u.y; au[c4+2][row] = u.z; au[c4+3][row] = u.w;
    float4 v = *reinterpret_cast<const float4*>(wd + (size_t)row * 512 + i0 + c4);
    bd[row][c4+0] = v.x; bd[row][c4+1] = v.y; bd[row][c4+2] = v.z; bd[row][c4+3] = v.w;
  }
  __syncthreads();
  const int tr = t >> 4, tc = t & 15;
  float acc[4][4] = {};
#pragma unroll
  for(int kk = 0; kk < 64; kk++){
    const float4 a4 = *reinterpret_cast<const float4*>(&au[kk][tr << 2]);
    const float4 b4 = *reinterpret_cast<const float4*>(&bd[kk][tc << 2]);
    const float av_[4] = {a4.x, a4.y, a4.z, a4.w};
    const float bv_[4] = {b4.x, b4.y, b4.z, b4.w};
#pragma unroll
    for(int i = 0; i < 4; i++)
#pragma unroll
      for(int j = 0; j < 4; j++) acc[i][j] = fmaf(av_[i], bv_[j], acc[i][j]);
  }
#pragma unroll
  for(int i = 0; i < 4; i++){
    ushort4 o;
    o.x = f2bf(acc[i][0]); o.y = f2bf(acc[i][1]); o.z = f2bf(acc[i][2]); o.w = f2bf(acc[i][3]);
    *reinterpret_cast<ushort4*>(dst + (size_t)(o0 + (tr << 2) + i) * 512 + i0 + (tc << 2)) = o;
  }
}

// ---------------- Wvo = 0.1 * w_od(64x512) @ w_vu(512x64), fp32, one block ----------------
__global__ __launch_bounds__(256) void wvo_kernel(const float* __restrict__ w_od,
                                                  const float* __restrict__ w_vu,
                                                  float* __restrict__ Wvo){
  __shared__ float As[16][68];
  __shared__ float Bs[16][68];
  const int t = threadIdx.x;
  const int tr = t >> 4, tc = t & 15;
  float acc[4][4] = {};
  for(int k0 = 0; k0 < 512; k0 += 16){
    __syncthreads();
#pragma unroll
    for(int q = 0; q < 4; q++){
      const int idx = q * 256 + t;
      const int kk = idx >> 6, l = idx & 63;
      As[kk][l] = w_od[(size_t)l * 512 + k0 + kk];
      Bs[kk][l] = w_vu[(size_t)(k0 + kk) * 64 + l];
    }
    __syncthreads();
#pragma unroll
    for(int kk = 0; kk < 16; kk++){
      const float4 a4 = *reinterpret_cast<const float4*>(&As[kk][tr << 2]);
      const float4 b4 = *reinterpret_cast<const float4*>(&Bs[kk][tc << 2]);
      const float av_[4] = {a4.x, a4.y, a4.z, a4.w};
      const float bv_[4] = {b4.x, b4.y, b4.z, b4.w};
#pragma unroll
      for(int i = 0; i < 4; i++)
#pragma unroll
        for(int j = 0; j < 4; j++) acc[i][j] = fmaf(av_[i], bv_[j], acc[i][j]);
    }
  }
#pragma unroll
  for(int i = 0; i < 4; i++)
#pragma unroll
    for(int j = 0; j < 4; j++)
      Wvo[(size_t)((tr << 2) + i) * 64 + (tc << 2) + j] = 0.1f * acc[i][j];
}

// ---------------- QK+Vlow GEMM: 2-phase dbuf. C = xb(32768x512) @ Wall^T(1152x512) ----------------
__global__ __launch_bounds__(256) void qkvlow_gemm(const u16* __restrict__ Am, const u16* __restrict__ Bm,
                                                   u16* __restrict__ Qt, u16* __restrict__ Kt,
                                                   u16* __restrict__ Vlowt, float* __restrict__ Ksum){
  __shared__ u16 As[2][4096];
  __shared__ u16 Bs[2][4096];
  const int t = threadIdx.x;
  const int wid = t >> 6, lane = t & 63;
  const int wr = wid >> 1, wc = wid & 1;
  const int bm = blockIdx.x << 7, bn = blockIdx.y << 7;
  f32x4 acc[4][4];
#pragma unroll
  for(int m = 0; m < 4; m++)
#pragma unroll
    for(int n = 0; n < 4; n++) acc[m][n] = f32x4{0.f, 0.f, 0.f, 0.f};
  const int frow = lane & 15;
  const int kg8  = (lane >> 4) << 3;
  const int c0 = t, c1 = t + 256;
  const size_t a0 = (size_t)(bm + (c0 >> 2)) * 512 + ((c0 & 3) << 3);
  const size_t a1 = (size_t)(bm + (c1 >> 2)) * 512 + ((c1 & 3) << 3);
  const size_t b0 = (size_t)(bn + (c0 >> 2)) * 512 + ((c0 & 3) << 3);
  const size_t b1 = (size_t)(bn + (c1 >> 2)) * 512 + ((c1 & 3) << 3);
#define QSTAGE(bf, k0) do{ \
    GLD16(Am + a0 + (k0), ((char*)&As[bf][0]) + (wid << 10)); \
    GLD16(Am + a1 + (k0), ((char*)&As[bf][0]) + 4096 + (wid << 10)); \
    GLD16(Bm + b0 + (k0), ((char*)&Bs[bf][0]) + (wid << 10)); \
    GLD16(Bm + b1 + (k0), ((char*)&Bs[bf][0]) + 4096 + (wid << 10)); }while(0)
#define QCOMP(bf) do{ \
    short8 af[4], bfr[4]; \
    _Pragma("unroll") \
    for(int m = 0; m < 4; m++){ \
      af[m]  = *reinterpret_cast<const short8*>(&As[bf][(((wr << 6) + (m << 4) + frow) << 5) + kg8]); \
      bfr[m] = *reinterpret_cast<const short8*>(&Bs[bf][(((wc << 6) + (m << 4) + frow) << 5) + kg8]); } \
    _Pragma("unroll") \
    for(int m = 0; m < 4; m++) \
      _Pragma("unroll") \
      for(int n = 0; n < 4; n++) \
        acc[m][n] = __builtin_amdgcn_mfma_f32_16x16x32_bf16(af[m], bfr[n], acc[m][n], 0, 0, 0); }while(0)
  QSTAGE(0, 0);
  __syncthreads();
  int cur = 0;
  for(int k0 = 32; k0 < 512; k0 += 32){
    QSTAGE(cur ^ 1, k0);
    QCOMP(cur);
    __syncthreads();
    cur ^= 1;
  }
  QCOMP(cur);
  const int cn = lane & 15, rb4 = (lane >> 4) << 2;
  const int b = bm >> 12;
#pragma unroll
  for(int nf = 0; nf < 4; nf++){
    const int col = bn + (wc << 6) + (nf << 4) + cn;
    u16* rowp;
    bool isK = false, isQorK = false;
    if(col < 512){
      rowp = Qt + ((((size_t)((b << 3) + (col >> 6)) << 6) + (col & 63)) << 12);
      isQorK = true;
    } else if(col < 1024){
      const int c = col - 512;
      rowp = Kt + ((((size_t)((b << 3) + (c >> 6)) << 6) + (c & 63)) << 12);
      isK = true; isQorK = true;
    } else {
      const int j = col - 1024;
      if(j >= 64) continue;
      rowp = Vlowt + ((size_t)((b << 6) + j) << 12);
    }
    float ks = 0.f;
#pragma unroll
    for(int mf = 0; mf < 4; mf++){
      const int nn0 = (bm & 4095) + (wr << 6) + (mf << 4) + rb4;
      float v0 = acc[mf][nf][0], v1 = acc[mf][nf][1], v2 = acc[mf][nf][2], v3 = acc[mf][nf][3];
      if(isQorK){
        v0 = v0 > 0.f ? v0 + 1.f : __expf(v0);
        v1 = v1 > 0.f ? v1 + 1.f : __expf(v1);
        v2 = v2 > 0.f ? v2 + 1.f : __expf(v2);
        v3 = v3 > 0.f ? v3 + 1.f : __expf(v3);
      }
      if(isK) ks += v0 + v1 + v2 + v3;
      ushort4 o = {f2bf(v0), f2bf(v1), f2bf(v2), f2bf(v3)};
      *reinterpret_cast<ushort4*>(rowp + nn0) = o;
    }
    if(isK){
      ks += __shfl_xor(ks, 16);
      ks += __shfl_xor(ks, 32);
      if(lane < 16){
        const int c = col - 512;
        atomicAdd(Ksum + ((size_t)((b << 3) + (c >> 6)) << 6) + (c & 63), ks);
      }
    }
  }
#undef QSTAGE
#undef QCOMP
}

// ---------------- KVlow[bh][d][j] = sum_n Kt[bh,d,n]*Vlowt[b*64+j,n]; 2-phase dbuf ----------------
__global__ __launch_bounds__(256) void kvlow_gemm(const u16* __restrict__ Kt,
                                                  const u16* __restrict__ Vlowt,
                                                  float* __restrict__ KVlow){
  __shared__ u16 As[2][2048];
  __shared__ u16 Bs[2][2048];
  const int bh = blockIdx.x, sp = blockIdx.y;
  const int b = bh >> 3;
  const int t = threadIdx.x;
  const int wid = t >> 6, lane = t & 63;
  const int frow = lane & 15, kg8 = (lane >> 4) << 3;
  const size_t kbase = (size_t)bh << 18;
  const size_t vbase = (size_t)b << 18;
  const int srow = t >> 2, soff = (t & 3) << 3;
  const size_t asrc = kbase + ((size_t)srow << 12) + soff;
  const size_t bsrc = vbase + ((size_t)srow << 12) + soff;
  f32x4 acc[4];
#pragma unroll
  for(int n = 0; n < 4; n++) acc[n] = f32x4{0.f, 0.f, 0.f, 0.f};
#define KSTAGE(bf, n0) do{ \
    GLD16(Kt    + asrc + (n0), ((char*)&As[bf][0]) + (wid << 10)); \
    GLD16(Vlowt + bsrc + (n0), ((char*)&Bs[bf][0]) + (wid << 10)); }while(0)
#define KCOMP(bf) do{ \
    short8 af = *reinterpret_cast<const short8*>(&As[bf][(((wid << 4) + frow) << 5) + kg8]); \
    _Pragma("unroll") \
    for(int n = 0; n < 4; n++){ \
      short8 bf8 = *reinterpret_cast<const short8*>(&Bs[bf][(((n << 4) + frow) << 5) + kg8]); \
      acc[n] = __builtin_amdgcn_mfma_f32_16x16x32_bf16(af, bf8, acc[n], 0, 0, 0); } }while(0)
  const int nbeg = sp << 10;
  KSTAGE(0, nbeg);
  __syncthreads();
  int cur = 0;
  for(int n0 = nbeg + 32; n0 < nbeg + 1024; n0 += 32){
    KSTAGE(cur ^ 1, n0);
    KCOMP(cur);
    __syncthreads();
    cur ^= 1;
  }
  KCOMP(cur);
  const int cn = lane & 15, rb4 = (lane >> 4) << 2;
#pragma unroll
  for(int n = 0; n < 4; n++)
#pragma unroll
    for(int j = 0; j < 4; j++){
      const int d = (wid << 4) + rb4 + j;
      const int jj = (n << 4) + cn;
      atomicAdd(KVlow + ((size_t)bh << 12) + (size_t)d * 64 + jj, acc[n][j]);
    }
#undef KSTAGE
#undef KCOMP
}

// ---------------- KVt[bh][hd][d] = sum_j KVlow[bh][d][j] * w_vu[h*64+hd][j] ----------------
__global__ __launch_bounds__(256) void kv_apply(const float* __restrict__ KVlow,
                                                const float* __restrict__ w_vu,
                                                float* __restrict__ KVt){
  __shared__ float Kl[64][68];
  __shared__ float Wl[64][68];
  const int bh = blockIdx.x, h = bh & 7;
  const int t = threadIdx.x;
#pragma unroll
  for(int q = 0; q < 4; q++){
    const int row = (q << 4) + (t >> 4);
    const int c4  = (t & 15) << 2;
    float4 v = *reinterpret_cast<const float4*>(KVlow + ((size_t)bh << 12) + (size_t)row * 64 + c4);
    Kl[c4+0][row] = v.x; Kl[c4+1][row] = v.y; Kl[c4+2][row] = v.z; Kl[c4+3][row] = v.w;
    float4 w = *reinterpret_cast<const float4*>(w_vu + (size_t)((h << 6) + row) * 64 + c4);
    Wl[c4+0][row] = w.x; Wl[c4+1][row] = w.y; Wl[c4+2][row] = w.z; Wl[c4+3][row] = w.w;
  }
  __syncthreads();
  const int tr = t >> 4, tc = t & 15;
  float acc[4][4] = {};
#pragma unroll
  for(int kk = 0; kk < 64; kk++){
    const float4 a4 = *reinterpret_cast<const float4*>(&Wl[kk][tr << 2]);
    const float4 b4 = *reinterpret_cast<const float4*>(&Kl[kk][tc << 2]);
    const float av_[4] = {a4.x, a4.y, a4.z, a4.w};
    const float bv_[4] = {b4.x, b4.y, b4.z, b4.w};
#pragma unroll
    for(int i = 0; i < 4; i++)
#pragma unroll
      for(int j = 0; j < 4; j++) acc[i][j] = fmaf(av_[i], bv_[j], acc[i][j]);
  }
#pragma unroll
  for(int i = 0; i < 4; i++){
    float4 o = {acc[i][0], acc[i][1], acc[i][2], acc[i][3]};
    *reinterpret_cast<float4*>(KVt + ((size_t)bh << 12) + (size_t)((tr << 2) + i) * 64 + (tc << 2)) = o;
  }
}

// ---------------- bias_pv: Pv[kz][i][c] = sum_{k half kz} attn[i,k]*Vlowt[c,k]; 2-phase dbuf ----------------
__global__ __launch_bounds__(256) void bias_pv(const u16* __restrict__ Am,
                                               const u16* __restrict__ Bm,
                                               float* __restrict__ Pv){
  __shared__ u16 As[2][4096];
  __shared__ u16 Bs[2][4096];
  const int t = threadIdx.x;
  const int wid = t >> 6, lane = t & 63;
  const int wr = wid >> 1, wc = wid & 1;
  const int bm = blockIdx.x << 7, bn = blockIdx.y << 7, kz = blockIdx.z;
  f32x4 acc[4][4];
#pragma unroll
  for(int m = 0; m < 4; m++)
#pragma unroll
    for(int n = 0; n < 4; n++) acc[m][n] = f32x4{0.f, 0.f, 0.f, 0.f};
  const int frow = lane & 15;
  const int kg8  = (lane >> 4) << 3;
  const int c0 = t, c1 = t + 256;
  const size_t a0 = ((size_t)(bm + (c0 >> 2)) << 12) + ((c0 & 3) << 3);
  const size_t a1 = ((size_t)(bm + (c1 >> 2)) << 12) + ((c1 & 3) << 3);
  const size_t b0 = ((size_t)(bn + (c0 >> 2)) << 12) + ((c0 & 3) << 3);
  const size_t b1 = ((size_t)(bn + (c1 >> 2)) << 12) + ((c1 & 3) << 3);
#define PSTAGE(bf, k0) do{ \
    GLD16(Am + a0 + (k0), ((char*)&As[bf][0]) + (wid << 10)); \
    GLD16(Am + a1 + (k0), ((char*)&As[bf][0]) + 4096 + (wid << 10)); \
    GLD16(Bm + b0 + (k0), ((char*)&Bs[bf][0]) + (wid << 10)); \
    GLD16(Bm + b1 + (k0), ((char*)&Bs[bf][0]) + 4096 + (wid << 10)); }while(0)
#define PCOMP(bf) do{ \
    short8 af[4], bfr[4]; \
    _Pragma("unroll") \
    for(int m = 0; m < 4; m++){ \
      af[m]  = *reinterpret_cast<const short8*>(&As[bf][(((wr << 6) + (m << 4) + frow) << 5) + kg8]); \
      bfr[m] = *reinterpret_cast<const short8*>(&Bs[bf][(((wc << 6) + (m << 4) + frow) << 5) + kg8]); } \
    _Pragma("unroll") \
    for(int m = 0; m < 4; m++) \
      _Pragma("unroll") \
      for(int n = 0; n < 4; n++) \
        acc[m][n] = __builtin_amdgcn_mfma_f32_16x16x32_bf16(af[m], bfr[n], acc[m][n], 0, 0, 0); }while(0)
  const int kbeg = kz << 11;
  PSTAGE(0, kbeg);
  __syncthreads();
  int cur = 0;
  for(int k0 = kbeg + 32; k0 < kbeg + 2048; k0 += 32){
    PSTAGE(cur ^ 1, k0);
    PCOMP(cur);
    __syncthreads();
    cur ^= 1;
  }
  PCOMP(cur);
  const int cn = lane & 15, rb4 = (lane >> 4) << 2;
  float* P = Pv + (size_t)kz * 2097152;
#pragma unroll
  for(int m = 0; m < 4; m++){
    const int row0 = bm + (wr << 6) + (m << 4) + rb4;
#pragma unroll
    for(int n = 0; n < 4; n++){
      const int col = bn + (wc << 6) + (n << 4) + cn;
#pragma unroll
      for(int j = 0; j < 4; j++)
        P[(size_t)(row0 + j) * 512 + col] = acc[m][n][j];
    }
  }
#undef PSTAGE
#undef PCOMP
}

// ---------------- linear attention: midb = bf16( (Q @ KVt^T)/clip(Q.Ksum) ) ----------------
__global__ __launch_bounds__(256) void linattn(const u16* __restrict__ Qt,
                                               const float* __restrict__ KVt,
                                               const float* __restrict__ Ksum,
                                               u16* __restrict__ midb){
  __shared__ float qs[64][64];
  __shared__ float kvs[64][64];
  __shared__ float nrm[64];
  __shared__ float ksl[64];
  const int nblk = blockIdx.x, bhi = blockIdx.y;
  const int b = bhi >> 3, h = bhi & 7;
  const int n0 = nblk << 6;
  const int t = threadIdx.x;
#pragma unroll
  for(int q = 0; q < 4; q++){
    const int row = (q << 4) + (t >> 4);
    const int c4  = (t & 15) << 2;
    ushort4 u = *reinterpret_cast<const ushort4*>(Qt + ((((size_t)bhi << 6) + row) << 12) + n0 + c4);
    qs[row][c4+0] = bf2f(u.x); qs[row][c4+1] = bf2f(u.y); qs[row][c4+2] = bf2f(u.z); qs[row][c4+3] = bf2f(u.w);
    float4 v = *reinterpret_cast<const float4*>(KVt + ((size_t)bhi << 12) + (row << 6) + c4);
    kvs[c4+0][row] = v.x; kvs[c4+1][row] = v.y; kvs[c4+2][row] = v.z; kvs[c4+3][row] = v.w;
  }
  if(t < 64) ksl[t] = Ksum[((size_t)bhi << 6) + t];
  __syncthreads();
  if(t < 64){
    float s = 0.f;
    for(int d = 0; d < 64; d++) s = fmaf(qs[d][t], ksl[d], s);
    nrm[t] = fmaxf(s, 1e-6f);
  }
  __syncthreads();
  const int tr = t >> 4, tc = t & 15;
  float acc[4][4] = {};
#pragma unroll
  for(int kk = 0; kk < 64; kk++){
    const float4 a4 = *reinterpret_cast<const float4*>(&qs[kk][tr << 2]);
    const float4 b4 = *reinterpret_cast<const float4*>(&kvs[kk][tc << 2]);
    const float av_[4] = {a4.x, a4.y, a4.z, a4.w};
    const float bv_[4] = {b4.x, b4.y, b4.z, b4.w};
#pragma unroll
    for(int i = 0; i < 4; i++)
#pragma unroll
      for(int j = 0; j < 4; j++) acc[i][j] = fmaf(av_[i], bv_[j], acc[i][j]);
  }
#pragma unroll
  for(int i = 0; i < 4; i++){
    const int gn = n0 + (tr << 2) + i;
    const float inv = 1.f / nrm[(tr << 2) + i];
    const size_t oi = (((size_t)b << 12) + gn) * 512 + h * 64 + (tc << 2);
    ushort4 o = {f2bf(acc[i][0] * inv), f2bf(acc[i][1] * inv),
                 f2bf(acc[i][2] * inv), f2bf(acc[i][3] * inv)};
    *reinterpret_cast<ushort4*>(midb + oi) = o;
  }
}

// ---------------- biaslow: G[(b,n)][l] = sum_j (Pv0+Pv1)[n][b*64+j] * Wvo[l][j] ----------------
__global__ __launch_bounds__(256) void biaslow(const float* __restrict__ Pv,
                                               const float* __restrict__ Wvo,
                                               float* __restrict__ G){
  __shared__ float Pl[64][68];
  __shared__ float Wl[64][68];
  const int nt = blockIdx.x, b = blockIdx.y;
  const int n0 = nt << 6;
  const int t = threadIdx.x;
#pragma unroll
  for(int q = 0; q < 4; q++){
    const int row = (q << 4) + (t >> 4);
    const int c4  = (t & 15) << 2;
    float4 v  = *reinterpret_cast<const float4*>(Pv + (size_t)(n0 + row) * 512 + (b << 6) + c4);
    float4 v2 = *reinterpret_cast<const float4*>(Pv + 2097152 + (size_t)(n0 + row) * 512 + (b << 6) + c4);
    Pl[c4+0][row] = v.x + v2.x; Pl[c4+1][row] = v.y + v2.y;
    Pl[c4+2][row] = v.z + v2.z; Pl[c4+3][row] = v.w + v2.w;
    float4 w = *reinterpret_cast<const float4*>(Wvo + (size_t)row * 64 + c4);
    Wl[c4+0][row] = w.x; Wl[c4+1][row] = w.y; Wl[c4+2][row] = w.z; Wl[c4+3][row] = w.w;
  }
  __syncthreads();
  const int tr = t >> 4, tc = t & 15;
  float acc[4][4] = {};
#pragma unroll
  for(int kk = 0; kk < 64; kk++){
    const float4 a4 = *reinterpret_cast<const float4*>(&Pl[kk][tr << 2]);
    const float4 b4 = *reinterpret_cast<const float4*>(&Wl[kk][tc << 2]);
    const float av_[4] = {a4.x, a4.y, a4.z, a4.w};
    const float bv_[4] = {b4.x, b4.y, b4.z, b4.w};
#pragma unroll
    for(int i = 0; i < 4; i++)
#pragma unroll
      for(int j = 0; j < 4; j++) acc[i][j] = fmaf(av_[i], bv_[j], acc[i][j]);
  }
#pragma unroll
  for(int i = 0; i < 4; i++){
    float4 o = {acc[i][0], acc[i][1], acc[i][2], acc[i][3]};
    *reinterpret_cast<float4*>(G + (size_t)(((size_t)b << 12) + n0 + (tr << 2) + i) * 64 + (tc << 2)) = o;
  }
}

// ---------------- down_gemm: Gb = bf16( midb(32768x512) @ wodb^T(64x512) + G ); dbuf As ----------------
__global__ __launch_bounds__(256) void down_gemm(const u16* __restrict__ Am,
                                                 const u16* __restrict__ Bw,
                                                 const float* __restrict__ Gin,
                                                 u16* __restrict__ Gb){
  __shared__ u16 As[2][4096];
  const int t = threadIdx.x;
  const int wid = t >> 6, lane = t & 63;
  const int bm = blockIdx.x << 7;
  const int frow = lane & 15, kg8 = (lane >> 4) << 3;
  f32x4 acc[2][4];
#pragma unroll
  for(int m = 0; m < 2; m++)
#pragma unroll
    for(int n = 0; n < 4; n++) acc[m][n] = f32x4{0.f, 0.f, 0.f, 0.f};
  const int c0 = t, c1 = t + 256;
  const size_t a0 = (size_t)(bm + (c0 >> 2)) * 512 + ((c0 & 3) << 3);
  const size_t a1 = (size_t)(bm + (c1 >> 2)) * 512 + ((c1 & 3) << 3);
#define DSTAGE(bf, k0) do{ \
    GLD16(Am + a0 + (k0), ((char*)&As[bf][0]) + (wid << 10)); \
    GLD16(Am + a1 + (k0), ((char*)&As[bf][0]) + 4096 + (wid << 10)); }while(0)
#define DCOMP(bf, k0) do{ \
    short8 af[2], bfr[4]; \
    _Pragma("unroll") \
    for(int m = 0; m < 2; m++) \
      af[m] = *reinterpret_cast<const short8*>(&As[bf][(((wid << 5) + (m << 4) + frow) << 5) + kg8]); \
    _Pragma("unroll") \
    for(int n = 0; n < 4; n++) \
      bfr[n] = *reinterpret_cast<const short8*>(Bw + (size_t)((n << 4) + frow) * 512 + (k0) + kg8); \
    _Pragma("unroll") \
    for(int m = 0; m < 2; m++) \
      _Pragma("unroll") \
      for(int n = 0; n < 4; n++) \
        acc[m][n] = __builtin_amdgcn_mfma_f32_16x16x32_bf16(af[m], bfr[n], acc[m][n], 0, 0, 0); }while(0)
  DSTAGE(0, 0);
  __syncthreads();
  int cur = 0;
  for(int k0 = 32; k0 < 512; k0 += 32){
    DSTAGE(cur ^ 1, k0);
    DCOMP(cur, k0 - 32);
    __syncthreads();
    cur ^= 1;
  }
  DCOMP(cur, 480);
  const int cn = lane & 15, rb4 = (lane >> 4) << 2;
#pragma unroll
  for(int m = 0; m < 2; m++){
#pragma unroll
    for(int n = 0; n < 4; n++){
      const int col = (n << 4) + cn;
#pragma unroll
      for(int j = 0; j < 4; j++){
        const int r = bm + (wid << 5) + (m << 4) + rb4 + j;
        const float v = acc[m][n][j] + Gin[(size_t)r * 64 + col];
        Gb[(size_t)r * 64 + col] = f2bf(v);
      }
    }
  }
#undef DSTAGE
#undef DCOMP
}

// ---------------- up_gemm: out(fp32 32768x512) = Gb(32768x64) @ woub^T(512x64); no LDS ----------------
__global__ __launch_bounds__(256) void up_gemm(const u16* __restrict__ Am,
                                               const u16* __restrict__ Bw,
                                               float* __restrict__ C){
  const int t = threadIdx.x;
  const int wid = t >> 6, lane = t & 63;
  const int wr = wid >> 1, wc = wid & 1;
  const int bm = blockIdx.x << 7, bn = blockIdx.y << 7;
  const int frow = lane & 15, kg8 = (lane >> 4) << 3;
  f32x4 acc[4][4];
#pragma unroll
  for(int m = 0; m < 4; m++)
#pragma unroll
    for(int n = 0; n < 4; n++) acc[m][n] = f32x4{0.f, 0.f, 0.f, 0.f};
  short8 af[4][2], bfr[4][2];
#pragma unroll
  for(int m = 0; m < 4; m++)
#pragma unroll
    for(int kk = 0; kk < 2; kk++)
      af[m][kk] = *reinterpret_cast<const short8*>(Am + (size_t)(bm + (wr << 6) + (m << 4) + frow) * 64 + (kk << 5) + kg8);
#pragma unroll
  for(int n = 0; n < 4; n++)
#pragma unroll
    for(int kk = 0; kk < 2; kk++)
      bfr[n][kk] = *reinterpret_cast<const short8*>(Bw + (size_t)(bn + (wc << 6) + (n << 4) + frow) * 64 + (kk << 5) + kg8);
#pragma unroll
  for(int m = 0; m < 4; m++)
#pragma unroll
    for(int n = 0; n < 4; n++){
      acc[m][n] = __builtin_amdgcn_mfma_f32_16x16x32_bf16(af[m][0], bfr[n][0], acc[m][n], 0, 0, 0);
      acc[m][n] = __builtin_amdgcn_mfma_f32_16x16x32_bf16(af[m][1], bfr[n][1], acc[m][n], 0, 0, 0);
    }
  const int cn = lane & 15, rb4 = (lane >> 4) << 2;
#pragma unroll
  for(int m = 0; m < 4; m++){
    const int row0 = bm + (wr << 6) + (m << 4) + rb4;
#pragma unroll
    for(int n = 0; n < 4; n++){
      const int col = bn + (wc << 6) + (n << 4) + cn;
#pragma unroll
      for(int j = 0; j < 4; j++)
        C[(size_t)(row0 + j) * 512 + col] = acc[m][n][j];
    }
  }
}

extern "C" void kernel_launch(void* const* d_in, const int* in_sizes, int n_in,
                              void* d_out, int out_size, void* d_ws, size_t ws_size,
                              hipStream_t stream){
  const float* x    = (const float*)d_in[0];
  const float* gb   = (const float*)d_in[1];
  const float* w_qd = (const float*)d_in[2];
  const float* w_qu = (const float*)d_in[3];
  const float* w_kd = (const float*)d_in[4];
  const float* w_ku = (const float*)d_in[5];
  const float* w_vd = (const float*)d_in[6];
  const float* w_vu = (const float*)d_in[7];
  const float* w_od = (const float*)d_in[8];
  const float* w_ou = (const float*)d_in[9];
  float* out = (float*)d_out;
  char* ws = (char*)d_ws;

  u16*   xb    = (u16*)  (ws);                  // 33554432
  u16*   Kt    = (u16*)  (ws + 33554432);       // 33554432
  u16*   Wall  = (u16*)  (ws + 67108864);       // 1179648
  u16*   wodb  = (u16*)  (ws + 68288512);       // 65536
  u16*   woub  = (u16*)  (ws + 68354048);       // 65536
  float* Wvo   = (float*)(ws + 68419584);       // 16384
  u16*   Qt    = (u16*)  (ws + 68435968);       // 33554432
  u16*   Vlowt = (u16*)  (ws + 101990400);      // 4194304
  u16*   attn  = (u16*)  (ws + 106184704);      // 33554432
  float* Pv    = (float*)(ws + 139739136);      // 2 x 8388608
  float* KVlow = (float*)(ws + 156516352);      // 1048576
  float* KVt   = (float*)(ws + 157564928);      // 1048576
  float* Ksum  = (float*)(ws + 158613504);      // 16384
  u16*   midb  = (u16*)  (ws);                  // overlaps xb (dead after qkvlow_gemm)
  float* G     = (float*)(ws + 33554432);       // overlaps Kt (dead after kvlow_gemm)
  u16*   Gb    = (u16*)  (ws + 41943040);       // within old Kt

  hipMemsetAsync(KVlow, 0, 2113536, stream);

  combine_w<<<dim3(8, 8), 256, 0, stream>>>(w_qu, w_qd, Wall);
  combine_w<<<dim3(8, 8), 256, 0, stream>>>(w_ku, w_kd, Wall + 262144);
  wvo_kernel<<<1, 256, 0, stream>>>(w_od, w_vu, Wvo);
  prep_w<<<64, 256, 0, stream>>>(w_od, w_ou, w_vd, wodb, woub, Wall + 524288);

  castf2b<<<8192, 256, 0, stream>>>(x, xb);
  softmax_rows<<<4096, 256, 0, stream>>>(gb, attn);

  qkvlow_gemm<<<dim3(256, 9), 256, 0, stream>>>(xb, Wall, Qt, Kt, Vlowt, Ksum);

  kvlow_gemm<<<dim3(64, 4), 256, 0, stream>>>(Kt, Vlowt, KVlow);
  kv_apply<<<64, 256, 0, stream>>>(KVlow, w_vu, KVt);

  bias_pv<<<dim3(32, 4, 2), 256, 0, stream>>>(attn, Vlowt, Pv);

  linattn<<<dim3(64, 64), 256, 0, stream>>>(Qt, KVt, Ksum, midb);

  biaslow<<<dim3(64, 8), 256, 0, stream>>>(Pv, Wvo, G);

  down_gemm<<<256, 256, 0, stream>>>(midb, wodb, G, Gb);

  up_gemm<<<dim3(256, 4), 256, 0, stream>>>(Gb, woub, out);
}

// Round 6
// 400.763 us; speedup vs baseline: 2.0561x; 1.1296x over previous
//
#include <hip/hip_runtime.h>

typedef unsigned short u16;
typedef __attribute__((ext_vector_type(8))) short short8;
typedef __attribute__((ext_vector_type(4))) float f32x4;

#define GLD16(g, l) __builtin_amdgcn_global_load_lds((const __attribute__((address_space(1))) void*)(g), (__attribute__((address_space(3))) void*)(l), 16, 0, 0)

__device__ __forceinline__ u16 f2bf(float f){
  unsigned x = __float_as_uint(f);
  return (u16)((x + 0x7FFFu + ((x >> 16) & 1u)) >> 16);
}
__device__ __forceinline__ float bf2f(u16 u){
  return __uint_as_float(((unsigned)u) << 16);
}

// ---------------- prep: wou->bf16 (16 blocks), wvd->bf16 padded to 128 rows (32 blocks) ----------------
__global__ __launch_bounds__(256) void prep_w(const float* __restrict__ w_ou,
                                              const float* __restrict__ w_vd,
                                              u16* __restrict__ woub,
                                              u16* __restrict__ wpad){
  const int bid = blockIdx.x, t = threadIdx.x;
  if(bid < 16){
    const size_t i = ((size_t)bid * 256 + t) * 8;
    float4 a = *reinterpret_cast<const float4*>(w_ou + i);
    float4 b = *reinterpret_cast<const float4*>(w_ou + i + 4);
    ushort4 o0 = {f2bf(a.x), f2bf(a.y), f2bf(a.z), f2bf(a.w)};
    ushort4 o1 = {f2bf(b.x), f2bf(b.y), f2bf(b.z), f2bf(b.w)};
    *reinterpret_cast<ushort4*>(woub + i) = o0;
    *reinterpret_cast<ushort4*>(woub + i + 4) = o1;
  } else {
    const int i = (bid - 16) * 256 + t;
    const int e = i * 8;
    const int r = e >> 9;
    ushort4 o0 = {0,0,0,0}, o1 = {0,0,0,0};
    if(r < 64){
      float4 a = *reinterpret_cast<const float4*>(w_vd + e);
      float4 b = *reinterpret_cast<const float4*>(w_vd + e + 4);
      o0 = ushort4{f2bf(a.x), f2bf(a.y), f2bf(a.z), f2bf(a.w)};
      o1 = ushort4{f2bf(b.x), f2bf(b.y), f2bf(b.z), f2bf(b.w)};
    }
    *reinterpret_cast<ushort4*>(wpad + e) = o0;
    *reinterpret_cast<ushort4*>(wpad + e + 4) = o1;
  }
}

// ---------------- x fp32 -> bf16 ----------------
__global__ __launch_bounds__(256) void castf2b(const float* __restrict__ src, u16* __restrict__ dst){
  const size_t i = ((size_t)blockIdx.x * 256 + threadIdx.x) * 8;
  float4 a = *reinterpret_cast<const float4*>(src + i);
  float4 b = *reinterpret_cast<const float4*>(src + i + 4);
  ushort4 o0 = {f2bf(a.x), f2bf(a.y), f2bf(a.z), f2bf(a.w)};
  ushort4 o1 = {f2bf(b.x), f2bf(b.y), f2bf(b.z), f2bf(b.w)};
  *reinterpret_cast<ushort4*>(dst + i) = o0;
  *reinterpret_cast<ushort4*>(dst + i + 4) = o1;
}

// ---------------- softmax over graph_bias rows -> bf16 attn ----------------
__global__ __launch_bounds__(256) void softmax_rows(const float* __restrict__ gb,
                                                    u16* __restrict__ attn){
  const int row = blockIdx.x;
  const float* rp = gb + (size_t)row * 4096;
  u16* op = attn + (size_t)row * 4096;
  const int t = threadIdx.x;
  float4 v[4];
  float mx = -3.4e38f;
#pragma unroll
  for(int k = 0; k < 4; k++){
    v[k] = *reinterpret_cast<const float4*>(rp + k*1024 + t*4);
    mx = fmaxf(mx, fmaxf(fmaxf(v[k].x, v[k].y), fmaxf(v[k].z, v[k].w)));
  }
#pragma unroll
  for(int off = 32; off > 0; off >>= 1) mx = fmaxf(mx, __shfl_xor(mx, off, 64));
  __shared__ float sred[4];
  __shared__ float sred2[4];
  const int wid = t >> 6, lane = t & 63;
  if(lane == 0) sred[wid] = mx;
  __syncthreads();
  mx = fmaxf(fmaxf(sred[0], sred[1]), fmaxf(sred[2], sred[3]));
  float s = 0.f;
#pragma unroll
  for(int k = 0; k < 4; k++){
    v[k].x = __expf(v[k].x - mx); v[k].y = __expf(v[k].y - mx);
    v[k].z = __expf(v[k].z - mx); v[k].w = __expf(v[k].w - mx);
    s += v[k].x + v[k].y + v[k].z + v[k].w;
  }
#pragma unroll
  for(int off = 32; off > 0; off >>= 1) s += __shfl_xor(s, off, 64);
  if(lane == 0) sred2[wid] = s;
  __syncthreads();
  s = sred2[0] + sred2[1] + sred2[2] + sred2[3];
  const float inv = 1.f / s;
#pragma unroll
  for(int k = 0; k < 4; k++){
    ushort4 o;
    o.x = f2bf(v[k].x * inv); o.y = f2bf(v[k].y * inv);
    o.z = f2bf(v[k].z * inv); o.w = f2bf(v[k].w * inv);
    *reinterpret_cast<ushort4*>(op + k*1024 + t*4) = o;
  }
}

// ---------------- combine low-rank pair: W = wu(512x64) @ wd(64x512), bf16 out ----------------
__global__ __launch_bounds__(256) void combine_w(const float* __restrict__ wu,
                                                 const float* __restrict__ wd,
                                                 u16* __restrict__ dst){
  __shared__ float au[64][68];
  __shared__ float bd[64][68];
  const int t = threadIdx.x;
  const int o0 = blockIdx.x << 6, i0 = blockIdx.y << 6;
#pragma unroll
  for(int q = 0; q < 4; q++){
    const int row = (q << 4) + (t >> 4);
    const int c4  = (t & 15) << 2;
    float4 u = *reinterpret_cast<const float4*>(wu + (size_t)(o0 + row) * 64 + c4);
    au[c4+0][row] = u.x; au[c4+1][row] = u.y; au[c4+2][row] = u.z; au[c4+3][row] = u.w;
    float4 v = *reinterpret_cast<const float4*>(wd + (size_t)row * 512 + i0 + c4);
    bd[row][c4+0] = v.x; bd[row][c4+1] = v.y; bd[row][c4+2] = v.z; bd[row][c4+3] = v.w;
  }
  __syncthreads();
  const int tr = t >> 4, tc = t & 15;
  float acc[4][4] = {};
#pragma unroll
  for(int kk = 0; kk < 64; kk++){
    const float4 a4 = *reinterpret_cast<const float4*>(&au[kk][tr << 2]);
    const float4 b4 = *reinterpret_cast<const float4*>(&bd[kk][tc << 2]);
    const float av_[4] = {a4.x, a4.y, a4.z, a4.w};
    const float bv_[4] = {b4.x, b4.y, b4.z, b4.w};
#pragma unroll
    for(int i = 0; i < 4; i++)
#pragma unroll
      for(int j = 0; j < 4; j++) acc[i][j] = fmaf(av_[i], bv_[j], acc[i][j]);
  }
#pragma unroll
  for(int i = 0; i < 4; i++){
    ushort4 o;
    o.x = f2bf(acc[i][0]); o.y = f2bf(acc[i][1]); o.z = f2bf(acc[i][2]); o.w = f2bf(acc[i][3]);
    *reinterpret_cast<ushort4*>(dst + (size_t)(o0 + (tr << 2) + i) * 512 + i0 + (tc << 2)) = o;
  }
}

// ---------------- Wvob = bf16( 0.1 * w_od(64x512) @ w_vu(512x64) ), one block ----------------
__global__ __launch_bounds__(256) void wvo_kernel(const float* __restrict__ w_od,
                                                  const float* __restrict__ w_vu,
                                                  u16* __restrict__ Wvob){
  __shared__ float As[16][68];
  __shared__ float Bs[16][68];
  const int t = threadIdx.x;
  const int tr = t >> 4, tc = t & 15;
  float acc[4][4] = {};
  for(int k0 = 0; k0 < 512; k0 += 16){
    __syncthreads();
#pragma unroll
    for(int q = 0; q < 4; q++){
      const int idx = q * 256 + t;
      const int kk = idx >> 6, l = idx & 63;
      As[kk][l] = w_od[(size_t)l * 512 + k0 + kk];
      Bs[kk][l] = w_vu[(size_t)(k0 + kk) * 64 + l];
    }
    __syncthreads();
#pragma unroll
    for(int kk = 0; kk < 16; kk++){
      const float4 a4 = *reinterpret_cast<const float4*>(&As[kk][tr << 2]);
      const float4 b4 = *reinterpret_cast<const float4*>(&Bs[kk][tc << 2]);
      const float av_[4] = {a4.x, a4.y, a4.z, a4.w};
      const float bv_[4] = {b4.x, b4.y, b4.z, b4.w};
#pragma unroll
      for(int i = 0; i < 4; i++)
#pragma unroll
        for(int j = 0; j < 4; j++) acc[i][j] = fmaf(av_[i], bv_[j], acc[i][j]);
    }
  }
#pragma unroll
  for(int i = 0; i < 4; i++){
    ushort4 o = {f2bf(0.1f*acc[i][0]), f2bf(0.1f*acc[i][1]), f2bf(0.1f*acc[i][2]), f2bf(0.1f*acc[i][3])};
    *reinterpret_cast<ushort4*>(Wvob + (size_t)((tr << 2) + i) * 64 + (tc << 2)) = o;
  }
}

// ---------------- U_h[l][j] = sum_m w_od[l][h*64+m] * w_vu[h*64+m][j]; 8 blocks ----------------
__global__ __launch_bounds__(256) void u_kernel(const float* __restrict__ w_od,
                                                const float* __restrict__ w_vu,
                                                float* __restrict__ U){
  __shared__ float Am[64][68];   // [m][l]
  __shared__ float Bm[64][68];   // [m][j]
  const int h = blockIdx.x;
  const int t = threadIdx.x;
#pragma unroll
  for(int q = 0; q < 4; q++){
    const int row = (q << 4) + (t >> 4);
    const int c4  = (t & 15) << 2;
    float4 a = *reinterpret_cast<const float4*>(w_od + (size_t)row * 512 + (h << 6) + c4);
    Am[c4+0][row] = a.x; Am[c4+1][row] = a.y; Am[c4+2][row] = a.z; Am[c4+3][row] = a.w;
    float4 bv = *reinterpret_cast<const float4*>(w_vu + (size_t)((h << 6) + row) * 64 + c4);
    *reinterpret_cast<float4*>(&Bm[row][c4]) = bv;
  }
  __syncthreads();
  const int tr = t >> 4, tc = t & 15;
  float acc[4][4] = {};
#pragma unroll
  for(int kk = 0; kk < 64; kk++){
    const float4 a4 = *reinterpret_cast<const float4*>(&Am[kk][tr << 2]);
    const float4 b4 = *reinterpret_cast<const float4*>(&Bm[kk][tc << 2]);
    const float av_[4] = {a4.x, a4.y, a4.z, a4.w};
    const float bv_[4] = {b4.x, b4.y, b4.z, b4.w};
#pragma unroll
    for(int i = 0; i < 4; i++)
#pragma unroll
      for(int j = 0; j < 4; j++) acc[i][j] = fmaf(av_[i], bv_[j], acc[i][j]);
  }
#pragma unroll
  for(int i = 0; i < 4; i++){
    float4 o = {acc[i][0], acc[i][1], acc[i][2], acc[i][3]};
    *reinterpret_cast<float4*>(U + ((size_t)h << 12) + (size_t)((tr << 2) + i) * 64 + (tc << 2)) = o;
  }
}

// ---------------- QK+Vlow GEMM: 2-phase dbuf; Q stored NATURAL [b*4096+n][512] ----------------
__global__ __launch_bounds__(256) void qkvlow_gemm(const u16* __restrict__ Am, const u16* __restrict__ Bm,
                                                   u16* __restrict__ Qb, u16* __restrict__ Kt,
                                                   u16* __restrict__ Vlowt, float* __restrict__ Ksum){
  __shared__ u16 As[2][4096];
  __shared__ u16 Bs[2][4096];
  const int t = threadIdx.x;
  const int wid = t >> 6, lane = t & 63;
  const int wr = wid >> 1, wc = wid & 1;
  const int bm = blockIdx.x << 7, bn = blockIdx.y << 7;
  f32x4 acc[4][4];
#pragma unroll
  for(int m = 0; m < 4; m++)
#pragma unroll
    for(int n = 0; n < 4; n++) acc[m][n] = f32x4{0.f, 0.f, 0.f, 0.f};
  const int frow = lane & 15;
  const int kg8  = (lane >> 4) << 3;
  const int c0 = t, c1 = t + 256;
  const size_t a0 = (size_t)(bm + (c0 >> 2)) * 512 + ((c0 & 3) << 3);
  const size_t a1 = (size_t)(bm + (c1 >> 2)) * 512 + ((c1 & 3) << 3);
  const size_t b0 = (size_t)(bn + (c0 >> 2)) * 512 + ((c0 & 3) << 3);
  const size_t b1 = (size_t)(bn + (c1 >> 2)) * 512 + ((c1 & 3) << 3);
#define QSTAGE(bf, k0) do{ \
    GLD16(Am + a0 + (k0), ((char*)&As[bf][0]) + (wid << 10)); \
    GLD16(Am + a1 + (k0), ((char*)&As[bf][0]) + 4096 + (wid << 10)); \
    GLD16(Bm + b0 + (k0), ((char*)&Bs[bf][0]) + (wid << 10)); \
    GLD16(Bm + b1 + (k0), ((char*)&Bs[bf][0]) + 4096 + (wid << 10)); }while(0)
#define QCOMP(bf) do{ \
    short8 af[4], bfr[4]; \
    _Pragma("unroll") \
    for(int m = 0; m < 4; m++){ \
      af[m]  = *reinterpret_cast<const short8*>(&As[bf][(((wr << 6) + (m << 4) + frow) << 5) + kg8]); \
      bfr[m] = *reinterpret_cast<const short8*>(&Bs[bf][(((wc << 6) + (m << 4) + frow) << 5) + kg8]); } \
    _Pragma("unroll") \
    for(int m = 0; m < 4; m++) \
      _Pragma("unroll") \
      for(int n = 0; n < 4; n++) \
        acc[m][n] = __builtin_amdgcn_mfma_f32_16x16x32_bf16(af[m], bfr[n], acc[m][n], 0, 0, 0); }while(0)
  QSTAGE(0, 0);
  __syncthreads();
  int cur = 0;
  for(int k0 = 32; k0 < 512; k0 += 32){
    QSTAGE(cur ^ 1, k0);
    QCOMP(cur);
    __syncthreads();
    cur ^= 1;
  }
  QCOMP(cur);
  const int cn = lane & 15, rb4 = (lane >> 4) << 2;
  const int b = bm >> 12;
#pragma unroll
  for(int nf = 0; nf < 4; nf++){
    const int col = bn + (wc << 6) + (nf << 4) + cn;
    if(col < 512){
      // Q: ELU+1, natural store
      u16* qp = Qb + col;
#pragma unroll
      for(int mf = 0; mf < 4; mf++){
        const int row0 = bm + (wr << 6) + (mf << 4) + rb4;
#pragma unroll
        for(int j = 0; j < 4; j++){
          float v = acc[mf][nf][j];
          v = v > 0.f ? v + 1.f : __expf(v);
          qp[(size_t)(row0 + j) << 9] = f2bf(v);
        }
      }
    } else if(col < 1024){
      // K: ELU+1, transposed store + Ksum
      const int c = col - 512;
      u16* rowp = Kt + ((((size_t)((b << 3) + (c >> 6)) << 6) + (c & 63)) << 12);
      float ks = 0.f;
#pragma unroll
      for(int mf = 0; mf < 4; mf++){
        const int nn0 = (bm & 4095) + (wr << 6) + (mf << 4) + rb4;
        float v0 = acc[mf][nf][0], v1 = acc[mf][nf][1], v2 = acc[mf][nf][2], v3 = acc[mf][nf][3];
        v0 = v0 > 0.f ? v0 + 1.f : __expf(v0);
        v1 = v1 > 0.f ? v1 + 1.f : __expf(v1);
        v2 = v2 > 0.f ? v2 + 1.f : __expf(v2);
        v3 = v3 > 0.f ? v3 + 1.f : __expf(v3);
        ks += v0 + v1 + v2 + v3;
        ushort4 o = {f2bf(v0), f2bf(v1), f2bf(v2), f2bf(v3)};
        *reinterpret_cast<ushort4*>(rowp + nn0) = o;
      }
      ks += __shfl_xor(ks, 16);
      ks += __shfl_xor(ks, 32);
      if(lane < 16)
        atomicAdd(Ksum + ((size_t)((b << 3) + (c >> 6)) << 6) + (c & 63), ks);
    } else {
      const int j = col - 1024;
      if(j >= 64) continue;
      u16* rowp = Vlowt + ((size_t)((b << 6) + j) << 12);
#pragma unroll
      for(int mf = 0; mf < 4; mf++){
        const int nn0 = (bm & 4095) + (wr << 6) + (mf << 4) + rb4;
        ushort4 o = {f2bf(acc[mf][nf][0]), f2bf(acc[mf][nf][1]),
                     f2bf(acc[mf][nf][2]), f2bf(acc[mf][nf][3])};
        *reinterpret_cast<ushort4*>(rowp + nn0) = o;
      }
    }
  }
#undef QSTAGE
#undef QCOMP
}

// ---------------- KVlow[bh][d][j] = sum_n Kt*Vlowt; 2-phase dbuf; split-n 8 ----------------
__global__ __launch_bounds__(256) void kvlow_gemm(const u16* __restrict__ Kt,
                                                  const u16* __restrict__ Vlowt,
                                                  float* __restrict__ KVlow){
  __shared__ u16 As[2][2048];
  __shared__ u16 Bs[2][2048];
  const int bh = blockIdx.x, sp = blockIdx.y;
  const int b = bh >> 3;
  const int t = threadIdx.x;
  const int wid = t >> 6, lane = t & 63;
  const int frow = lane & 15, kg8 = (lane >> 4) << 3;
  const size_t kbase = (size_t)bh << 18;
  const size_t vbase = (size_t)b << 18;
  const int srow = t >> 2, soff = (t & 3) << 3;
  const size_t asrc = kbase + ((size_t)srow << 12) + soff;
  const size_t bsrc = vbase + ((size_t)srow << 12) + soff;
  f32x4 acc[4];
#pragma unroll
  for(int n = 0; n < 4; n++) acc[n] = f32x4{0.f, 0.f, 0.f, 0.f};
#define KSTAGE(bf, n0) do{ \
    GLD16(Kt    + asrc + (n0), ((char*)&As[bf][0]) + (wid << 10)); \
    GLD16(Vlowt + bsrc + (n0), ((char*)&Bs[bf][0]) + (wid << 10)); }while(0)
#define KCOMP(bf) do{ \
    short8 af = *reinterpret_cast<const short8*>(&As[bf][(((wid << 4) + frow) << 5) + kg8]); \
    _Pragma("unroll") \
    for(int n = 0; n < 4; n++){ \
      short8 bf8 = *reinterpret_cast<const short8*>(&Bs[bf][(((n << 4) + frow) << 5) + kg8]); \
      acc[n] = __builtin_amdgcn_mfma_f32_16x16x32_bf16(af, bf8, acc[n], 0, 0, 0); } }while(0)
  const int nbeg = sp << 9;
  KSTAGE(0, nbeg);
  __syncthreads();
  int cur = 0;
  for(int n0 = nbeg + 32; n0 < nbeg + 512; n0 += 32){
    KSTAGE(cur ^ 1, n0);
    KCOMP(cur);
    __syncthreads();
    cur ^= 1;
  }
  KCOMP(cur);
  const int cn = lane & 15, rb4 = (lane >> 4) << 2;
#pragma unroll
  for(int n = 0; n < 4; n++)
#pragma unroll
    for(int j = 0; j < 4; j++){
      const int d = (wid << 4) + rb4 + j;
      const int jj = (n << 4) + cn;
      atomicAdd(KVlow + ((size_t)bh << 12) + (size_t)d * 64 + jj, acc[n][j]);
    }
#undef KSTAGE
#undef KCOMP
}

// ---------------- Tt[bh][l][d] = bf16( sum_j KVlow[bh][d][j] * U[h][l][j] ); 64 blocks ----------------
__global__ __launch_bounds__(256) void t_kernel(const float* __restrict__ KVlow,
                                                const float* __restrict__ U,
                                                u16* __restrict__ Tt){
  __shared__ float Kl[64][68];   // [j][d]
  __shared__ float Wl[64][68];   // [j][l]
  const int bh = blockIdx.x, h = bh & 7;
  const int t = threadIdx.x;
#pragma unroll
  for(int q = 0; q < 4; q++){
    const int row = (q << 4) + (t >> 4);
    const int c4  = (t & 15) << 2;
    float4 v = *reinterpret_cast<const float4*>(KVlow + ((size_t)bh << 12) + ((size_t)row << 6) + c4);
    Kl[c4+0][row] = v.x; Kl[c4+1][row] = v.y; Kl[c4+2][row] = v.z; Kl[c4+3][row] = v.w;
    float4 w = *reinterpret_cast<const float4*>(U + ((size_t)h << 12) + ((size_t)row << 6) + c4);
    Wl[c4+0][row] = w.x; Wl[c4+1][row] = w.y; Wl[c4+2][row] = w.z; Wl[c4+3][row] = w.w;
  }
  __syncthreads();
  const int tr = t >> 4, tc = t & 15;
  float acc[4][4] = {};
#pragma unroll
  for(int kk = 0; kk < 64; kk++){
    const float4 a4 = *reinterpret_cast<const float4*>(&Wl[kk][tr << 2]);
    const float4 b4 = *reinterpret_cast<const float4*>(&Kl[kk][tc << 2]);
    const float av_[4] = {a4.x, a4.y, a4.z, a4.w};
    const float bv_[4] = {b4.x, b4.y, b4.z, b4.w};
#pragma unroll
    for(int i = 0; i < 4; i++)
#pragma unroll
      for(int j = 0; j < 4; j++) acc[i][j] = fmaf(av_[i], bv_[j], acc[i][j]);
  }
#pragma unroll
  for(int i = 0; i < 4; i++){
    ushort4 o = {f2bf(acc[i][0]), f2bf(acc[i][1]), f2bf(acc[i][2]), f2bf(acc[i][3])};
    *reinterpret_cast<ushort4*>(Tt + ((size_t)bh << 12) + (size_t)((tr << 2) + i) * 64 + (tc << 2)) = o;
  }
}

// ---------------- bias_pv: Pv[kz][i][c] = sum_{k in quarter kz} attn[i,k]*Vlowt[c,k]; kz=4 ----------------
__global__ __launch_bounds__(256) void bias_pv(const u16* __restrict__ Am,
                                               const u16* __restrict__ Bm,
                                               float* __restrict__ Pv){
  __shared__ u16 As[2][4096];
  __shared__ u16 Bs[2][4096];
  const int t = threadIdx.x;
  const int wid = t >> 6, lane = t & 63;
  const int wr = wid >> 1, wc = wid & 1;
  const int bm = blockIdx.x << 7, bn = blockIdx.y << 7, kz = blockIdx.z;
  f32x4 acc[4][4];
#pragma unroll
  for(int m = 0; m < 4; m++)
#pragma unroll
    for(int n = 0; n < 4; n++) acc[m][n] = f32x4{0.f, 0.f, 0.f, 0.f};
  const int frow = lane & 15;
  const int kg8  = (lane >> 4) << 3;
  const int c0 = t, c1 = t + 256;
  const size_t a0 = ((size_t)(bm + (c0 >> 2)) << 12) + ((c0 & 3) << 3);
  const size_t a1 = ((size_t)(bm + (c1 >> 2)) << 12) + ((c1 & 3) << 3);
  const size_t b0 = ((size_t)(bn + (c0 >> 2)) << 12) + ((c0 & 3) << 3);
  const size_t b1 = ((size_t)(bn + (c1 >> 2)) << 12) + ((c1 & 3) << 3);
#define PSTAGE(bf, k0) do{ \
    GLD16(Am + a0 + (k0), ((char*)&As[bf][0]) + (wid << 10)); \
    GLD16(Am + a1 + (k0), ((char*)&As[bf][0]) + 4096 + (wid << 10)); \
    GLD16(Bm + b0 + (k0), ((char*)&Bs[bf][0]) + (wid << 10)); \
    GLD16(Bm + b1 + (k0), ((char*)&Bs[bf][0]) + 4096 + (wid << 10)); }while(0)
#define PCOMP(bf) do{ \
    short8 af[4], bfr[4]; \
    _Pragma("unroll") \
    for(int m = 0; m < 4; m++){ \
      af[m]  = *reinterpret_cast<const short8*>(&As[bf][(((wr << 6) + (m << 4) + frow) << 5) + kg8]); \
      bfr[m] = *reinterpret_cast<const short8*>(&Bs[bf][(((wc << 6) + (m << 4) + frow) << 5) + kg8]); } \
    _Pragma("unroll") \
    for(int m = 0; m < 4; m++) \
      _Pragma("unroll") \
      for(int n = 0; n < 4; n++) \
        acc[m][n] = __builtin_amdgcn_mfma_f32_16x16x32_bf16(af[m], bfr[n], acc[m][n], 0, 0, 0); }while(0)
  const int kbeg = kz << 10;
  PSTAGE(0, kbeg);
  __syncthreads();
  int cur = 0;
  for(int k0 = kbeg + 32; k0 < kbeg + 1024; k0 += 32){
    PSTAGE(cur ^ 1, k0);
    PCOMP(cur);
    __syncthreads();
    cur ^= 1;
  }
  PCOMP(cur);
  const int cn = lane & 15, rb4 = (lane >> 4) << 2;
  float* P = Pv + (size_t)kz * 2097152;
#pragma unroll
  for(int m = 0; m < 4; m++){
    const int row0 = bm + (wr << 6) + (m << 4) + rb4;
#pragma unroll
    for(int n = 0; n < 4; n++){
      const int col = bn + (wc << 6) + (n << 4) + cn;
#pragma unroll
      for(int j = 0; j < 4; j++)
        P[(size_t)(row0 + j) * 512 + col] = acc[m][n][j];
    }
  }
#undef PSTAGE
#undef PCOMP
}

// ---------------- tail_fused: out = [ sum_h (Q_h @ T_h^T)/nrm_h + Psum @ Wvo^T ] @ wou^T ----------------
// grid (64 n-tiles, 8 b), 256 threads. Chunked LDS layout [kc][row][32] for conflict-light b128.
__global__ __launch_bounds__(256) void tail_fused(const u16* __restrict__ Qb,
                                                  const float* __restrict__ Pv,
                                                  const u16* __restrict__ Tt,
                                                  const u16* __restrict__ Wvob,
                                                  const u16* __restrict__ woub,
                                                  const float* __restrict__ Ksum,
                                                  float* __restrict__ outp){
  __shared__ u16 qh[2][4096];    // [buf][kc*2048 + row*32 + k]
  __shared__ u16 ps[4096];       // Psum bf16 chunked
  __shared__ u16 gbl[4096];      // Glow bf16 chunked
  __shared__ float ksl[512];
  __shared__ float nrml[64];
  const int nt = blockIdx.x, b = blockIdx.y;
  const int n0 = nt << 6;
  const int t = threadIdx.x;
  const int wid = t >> 6, lane = t & 63;
  const int frow = lane & 15, kg8 = (lane >> 4) << 3;

  // Ksum -> LDS (contiguous per b: Ksum[(b*8+h)*64+d] = Ksum[b*512 + t])
  ksl[t]       = Ksum[(size_t)b * 512 + t];
  ksl[t + 256] = Ksum[(size_t)b * 512 + 256 + t];

  // Psum = sum of 4 Pv slabs -> ps (bf16, chunked)
  {
    const int r = t >> 2, jc = (t & 3) << 4;
    const float* p0 = Pv + ((size_t)(n0 + r) << 9) + (b << 6) + jc;
#pragma unroll
    for(int qq = 0; qq < 4; qq++){
      const int j = jc + (qq << 2);
      float4 s0 = *reinterpret_cast<const float4*>(p0 + (qq << 2));
      float4 s1 = *reinterpret_cast<const float4*>(p0 + (qq << 2) + 2097152);
      float4 s2 = *reinterpret_cast<const float4*>(p0 + (qq << 2) + 4194304);
      float4 s3 = *reinterpret_cast<const float4*>(p0 + (qq << 2) + 6291456);
      ushort4 o = {f2bf(s0.x + s1.x + s2.x + s3.x), f2bf(s0.y + s1.y + s2.y + s3.y),
                   f2bf(s0.z + s1.z + s2.z + s3.z), f2bf(s0.w + s1.w + s2.w + s3.w)};
      *reinterpret_cast<ushort4*>(&ps[((j >> 5) << 11) + (r << 5) + (j & 31)]) = o;
    }
  }

  // Q_h tile staging: 2 GLD16 rounds (kc halves), wave w covers rows w*16..w*16+15
  const size_t qrow = (size_t)((b << 12) + n0 + (wid << 4) + (lane >> 2)) << 9;
  const int qoff = (lane & 3) << 3;
#define STAGEQ(buf, h) do{ \
    GLD16(Qb + qrow + ((h) << 6) + qoff,      ((char*)&qh[buf][0]) + (wid << 10)); \
    GLD16(Qb + qrow + ((h) << 6) + 32 + qoff, ((char*)&qh[buf][0]) + 4096 + (wid << 10)); }while(0)

  STAGEQ(0, 0);
  __syncthreads();

  f32x4 glow[4];
#pragma unroll
  for(int n = 0; n < 4; n++) glow[n] = f32x4{0.f, 0.f, 0.f, 0.f};

  int buf = 0;
  for(int h = 0; h < 8; h++){
    if(h < 7) STAGEQ(buf ^ 1, h + 1);
    // nrm for head h: lane-mapped (n = wid*16 + lane>>2, part = lane&3 covers 16 d)
    {
      const int n_loc = (wid << 4) + (lane >> 2), part = lane & 3;
      float s = 0.f;
#pragma unroll
      for(int dd = 0; dd < 16; dd++){
        const int d = (part << 4) + dd;
        s += bf2f(qh[buf][((d >> 5) << 11) + (n_loc << 5) + (d & 31)]) * ksl[(h << 6) + d];
      }
      s += __shfl_xor(s, 1);
      s += __shfl_xor(s, 2);
      if(part == 0) nrml[n_loc] = 1.f / fmaxf(s, 1e-6f);
    }
    // per-head GEMM: rows wid*16..+15, 4 l-frags, K=64
    f32x4 ah[4];
#pragma unroll
    for(int n = 0; n < 4; n++) ah[n] = f32x4{0.f, 0.f, 0.f, 0.f};
#pragma unroll
    for(int kc = 0; kc < 2; kc++){
      short8 af = *reinterpret_cast<const short8*>(&qh[buf][(kc << 11) + (((wid << 4) + frow) << 5) + kg8]);
#pragma unroll
      for(int n = 0; n < 4; n++){
        short8 bf8 = *reinterpret_cast<const short8*>(
            Tt + ((((size_t)((b << 3) + h) << 6) + (n << 4) + frow) << 6) + (kc << 5) + kg8);
        ah[n] = __builtin_amdgcn_mfma_f32_16x16x32_bf16(af, bf8, ah[n], 0, 0, 0);
      }
    }
    // scale by 1/nrm (row-dependent) and accumulate
    float inv[4];
#pragma unroll
    for(int j = 0; j < 4; j++)
      inv[j] = nrml[(wid << 4) + ((lane >> 4) << 2) + j];
#pragma unroll
    for(int n = 0; n < 4; n++)
#pragma unroll
      for(int j = 0; j < 4; j++)
        glow[n][j] += ah[n][j] * inv[j];
    __syncthreads();
    buf ^= 1;
  }

  // bias: glow += Psum @ Wvob^T (K=64)
#pragma unroll
  for(int kc = 0; kc < 2; kc++){
    short8 af = *reinterpret_cast<const short8*>(&ps[(kc << 11) + (((wid << 4) + frow) << 5) + kg8]);
#pragma unroll
    for(int n = 0; n < 4; n++){
      short8 bf8 = *reinterpret_cast<const short8*>(Wvob + (((n << 4) + frow) << 6) + (kc << 5) + kg8);
      glow[n] = __builtin_amdgcn_mfma_f32_16x16x32_bf16(af, bf8, glow[n], 0, 0, 0);
    }
  }

  // Glow -> gbl bf16 chunked
#pragma unroll
  for(int n = 0; n < 4; n++)
#pragma unroll
    for(int j = 0; j < 4; j++){
      const int rloc = (wid << 4) + ((lane >> 4) << 2) + j;
      const int l = (n << 4) + (lane & 15);
      gbl[((l >> 5) << 11) + (rloc << 5) + (l & 31)] = f2bf(glow[n][j]);
    }
  __syncthreads();

  // up: out[64][512] = gbl @ woub^T; wave w -> cols w*128..+127
  f32x4 oc[4][8];
#pragma unroll
  for(int m = 0; m < 4; m++)
#pragma unroll
    for(int n = 0; n < 8; n++) oc[m][n] = f32x4{0.f, 0.f, 0.f, 0.f};
#pragma unroll
  for(int kc = 0; kc < 2; kc++){
    short8 af[4];
#pragma unroll
    for(int m = 0; m < 4; m++)
      af[m] = *reinterpret_cast<const short8*>(&gbl[(kc << 11) + (((m << 4) + frow) << 5) + kg8]);
#pragma unroll
    for(int n = 0; n < 8; n++){
      const int col = (wid << 7) + (n << 4) + frow;
      short8 bf8 = *reinterpret_cast<const short8*>(woub + ((size_t)col << 6) + (kc << 5) + kg8);
#pragma unroll
      for(int m = 0; m < 4; m++)
        oc[m][n] = __builtin_amdgcn_mfma_f32_16x16x32_bf16(af[m], bf8, oc[m][n], 0, 0, 0);
    }
  }
  const int cn = lane & 15, rb4 = (lane >> 4) << 2;
#pragma unroll
  for(int m = 0; m < 4; m++){
#pragma unroll
    for(int j = 0; j < 4; j++){
      const size_t row = (size_t)((b << 12) + n0 + (m << 4) + rb4 + j);
#pragma unroll
      for(int n = 0; n < 8; n++)
        outp[(row << 9) + (wid << 7) + (n << 4) + cn] = oc[m][n][j];
    }
  }
#undef STAGEQ
}

extern "C" void kernel_launch(void* const* d_in, const int* in_sizes, int n_in,
                              void* d_out, int out_size, void* d_ws, size_t ws_size,
                              hipStream_t stream){
  const float* x    = (const float*)d_in[0];
  const float* gb   = (const float*)d_in[1];
  const float* w_qd = (const float*)d_in[2];
  const float* w_qu = (const float*)d_in[3];
  const float* w_kd = (const float*)d_in[4];
  const float* w_ku = (const float*)d_in[5];
  const float* w_vd = (const float*)d_in[6];
  const float* w_vu = (const float*)d_in[7];
  const float* w_od = (const float*)d_in[8];
  const float* w_ou = (const float*)d_in[9];
  float* out = (float*)d_out;
  char* ws = (char*)d_ws;

  u16*   xb    = (u16*)  (ws);                  // 33554432 (dead after qkvlow)
  float* Pv    = (float*)(ws);                  // 4 x 8388608, overlaps xb
  u16*   Kt    = (u16*)  (ws + 33554432);       // 33554432
  u16*   Wall  = (u16*)  (ws + 67108864);       // 1179648
  u16*   woub  = (u16*)  (ws + 68288512);       // 65536
  u16*   Wvob  = (u16*)  (ws + 68354048);       // 8192
  float* U     = (float*)(ws + 68362240);       // 131072
  u16*   Tt    = (u16*)  (ws + 68493312);       // 524288
  float* KVlow = (float*)(ws + 69017600);       // 1048576
  float* Ksum  = (float*)(ws + 70066176);       // 16384
  u16*   Qb    = (u16*)  (ws + 70082560);       // 33554432
  u16*   Vlowt = (u16*)  (ws + 103636992);      // 4194304
  u16*   attn  = (u16*)  (ws + 107831296);      // 33554432

  hipMemsetAsync(KVlow, 0, 1048576 + 16384, stream);

  combine_w<<<dim3(8, 8), 256, 0, stream>>>(w_qu, w_qd, Wall);
  combine_w<<<dim3(8, 8), 256, 0, stream>>>(w_ku, w_kd, Wall + 262144);
  wvo_kernel<<<1, 256, 0, stream>>>(w_od, w_vu, Wvob);
  u_kernel<<<8, 256, 0, stream>>>(w_od, w_vu, U);
  prep_w<<<48, 256, 0, stream>>>(w_ou, w_vd, woub, Wall + 524288);

  castf2b<<<8192, 256, 0, stream>>>(x, xb);
  softmax_rows<<<4096, 256, 0, stream>>>(gb, attn);

  // Q (natural), K (transposed + Ksum), Vlow (transposed) in one MFMA GEMM
  qkvlow_gemm<<<dim3(256, 9), 256, 0, stream>>>(xb, Wall, Qb, Kt, Vlowt, Ksum);

  // KVlow = K^T @ Vlow per head (split-n=8), then fold U -> Tt
  kvlow_gemm<<<dim3(64, 8), 256, 0, stream>>>(Kt, Vlowt, KVlow);
  t_kernel<<<64, 256, 0, stream>>>(KVlow, U, Tt);

  // bias branch: Pv = attn @ Vlowt^T (split-K=4); Pv overlaps dead xb
  bias_pv<<<dim3(32, 4, 4), 256, 0, stream>>>(attn, Vlowt, Pv);

  // fused tail: linear attention + bias-low + down + up -> out
  tail_fused<<<dim3(64, 8), 256, 0, stream>>>(Qb, Pv, Tt, Wvob, woub, Ksum, out);
}